// Round 3
// baseline (327.885 us; speedup 1.0000x reference)
//
#include <hip/hip_runtime.h>

#define DIM 256
#define NH 8
#define HE 32          // head dim E
#define BALL 16        // ball size M
#define NBALLS 512
#define NM 8192

// ---------------------------------------------------------------------------
// K1: x' = x + rel @ W_pe^T + b_pe, rel = pos - per-ball mean(pos)
// one block per ball, 256 threads (one per feature dim)
// ---------------------------------------------------------------------------
__global__ __launch_bounds__(256) void k_posembed(
    const float* __restrict__ x, const float* __restrict__ pos,
    const float* __restrict__ Wpe, const float* __restrict__ bpe,
    float* __restrict__ xp) {
  __shared__ float ps[BALL * 3];
  __shared__ float mean_s[3];
  int ball = blockIdx.x;
  int tid = threadIdx.x;
  if (tid < BALL * 3) ps[tid] = pos[ball * BALL * 3 + tid];
  __syncthreads();
  if (tid < 3) {
    float s = 0.f;
    for (int m = 0; m < BALL; ++m) s += ps[m * 3 + tid];
    mean_s[tid] = s * (1.f / BALL);
  }
  __syncthreads();
  int d = tid;
  float w0 = Wpe[d * 3 + 0], w1 = Wpe[d * 3 + 1], w2 = Wpe[d * 3 + 2];
  float bp = bpe[d];
  float m0 = mean_s[0], m1 = mean_s[1], m2 = mean_s[2];
  for (int m = 0; m < BALL; ++m) {
    int t = ball * BALL + m;
    float r0 = ps[m * 3 + 0] - m0;
    float r1 = ps[m * 3 + 1] - m1;
    float r2 = ps[m * 3 + 2] - m2;
    xp[t * DIM + d] = x[t * DIM + d] + r0 * w0 + r1 * w1 + r2 * w2 + bp;
  }
}

// ---------------------------------------------------------------------------
// Shared fp32 tiled GEMM config: C[M,N] = A[M,K] * B[N,K]^T (+bias)
// BM=BN=64, BK=16, 256 threads, 4x4 microtile
// ---------------------------------------------------------------------------
#define BM 64
#define BN 64
#define BK 16
#define LDP 68  // padded leading dim: 2-way LDS aliasing max (free on CDNA4)

// K2: qkv = x' @ W_qkv^T + b_qkv, scattered to q/k/v buffers.
// output column o = h*96 + e*3 + c (c: 0=q,1=k,2=v), dest layout [H][nm][E]
__global__ __launch_bounds__(256) void k_qkv_gemm(
    const float* __restrict__ A, const float* __restrict__ B,
    const float* __restrict__ bias,
    float* __restrict__ qbuf, float* __restrict__ kbuf,
    float* __restrict__ vbuf) {
  __shared__ float As[BK][LDP];
  __shared__ float Bs[BK][LDP];
  int tid = threadIdx.x;
  int m0 = blockIdx.x * BM;
  int n0 = blockIdx.y * BN;
  int lr = tid >> 2;        // 0..63
  int lk = (tid & 3) * 4;   // 0,4,8,12
  int tx = tid & 15, ty = tid >> 4;
  float acc[4][4] = {};
  for (int k0 = 0; k0 < DIM; k0 += BK) {
    float4 av = *(const float4*)&A[(m0 + lr) * DIM + k0 + lk];
    float4 bv = *(const float4*)&B[(n0 + lr) * DIM + k0 + lk];
    As[lk + 0][lr] = av.x; As[lk + 1][lr] = av.y;
    As[lk + 2][lr] = av.z; As[lk + 3][lr] = av.w;
    Bs[lk + 0][lr] = bv.x; Bs[lk + 1][lr] = bv.y;
    Bs[lk + 2][lr] = bv.z; Bs[lk + 3][lr] = bv.w;
    __syncthreads();
#pragma unroll
    for (int k = 0; k < BK; ++k) {
      float4 a = *(const float4*)&As[k][ty * 4];
      float4 b = *(const float4*)&Bs[k][tx * 4];
      float ar[4] = {a.x, a.y, a.z, a.w};
      float br[4] = {b.x, b.y, b.z, b.w};
#pragma unroll
      for (int i = 0; i < 4; ++i)
#pragma unroll
        for (int j = 0; j < 4; ++j) acc[i][j] += ar[i] * br[j];
    }
    __syncthreads();
  }
#pragma unroll
  for (int i = 0; i < 4; ++i) {
    int t = m0 + ty * 4 + i;
#pragma unroll
    for (int j = 0; j < 4; ++j) {
      int o = n0 + tx * 4 + j;
      float val = acc[i][j] + bias[o];
      int c = o % 3;
      int r = o / 3;          // h*32 + e
      int e = r & 31, h = r >> 5;
      float* dst = (c == 0) ? qbuf : (c == 1) ? kbuf : vbuf;
      dst[(h * NM + t) * HE + e] = val;
    }
  }
}

// K2b: kmean[h][ball][e] = mean over m of kbuf[h][ball*16+m][e]
__global__ __launch_bounds__(256) void k_kmean(
    const float* __restrict__ kbuf, float* __restrict__ kmean) {
  int tid = threadIdx.x;
  int gb = blockIdx.x * 8 + (tid >> 5);  // h*512 + ball
  int e = tid & 31;
  int h = gb >> 9, ball = gb & 511;
  float s = 0.f;
#pragma unroll
  for (int m = 0; m < BALL; ++m)
    s += kbuf[(h * NM + ball * BALL + m) * HE + e];
  kmean[gb * HE + e] = s * (1.f / BALL);
}

// ---------------------------------------------------------------------------
// K3 v3: one thread = one query, q[32] in VGPRs. kmean is wave-uniform
// (every thread scans balls in the same order) -> compiler scalarizes the
// km loads to s_load into SGPRs; inner loop is pure v_fmac with SGPR src.
// Private running top-2 per thread: NO reduction, NO shuffles, NO LDS.
// 2 balls x 2 partial chains = 4 independent FMA chains to cover dep latency.
// ---------------------------------------------------------------------------
__global__ __launch_bounds__(256) void k_sim_topk(
    const float* __restrict__ qbuf, const float* __restrict__ kmean,
    int* __restrict__ topk) {
  int h = blockIdx.y;
  int t = blockIdx.x * 256 + threadIdx.x;

  float q[HE];
  const float4* qp = (const float4*)&qbuf[(h * NM + t) * HE];
#pragma unroll
  for (int u = 0; u < 8; ++u) {
    float4 v = qp[u];
    q[4 * u + 0] = v.x; q[4 * u + 1] = v.y;
    q[4 * u + 2] = v.z; q[4 * u + 3] = v.w;
  }

  const float* __restrict__ km = kmean + h * NBALLS * HE;
  float v0 = -1e30f, v1 = -1e30f;
  int i0 = 0, i1 = 0;

#pragma unroll 2
  for (int b = 0; b < NBALLS; b += 2) {
    const float* k0 = km + b * HE;
    const float* k1 = k0 + HE;
    float s0a = 0.f, s0b = 0.f, s1a = 0.f, s1b = 0.f;
#pragma unroll
    for (int e = 0; e < HE; e += 2) {
      s0a += q[e] * k0[e];
      s0b += q[e + 1] * k0[e + 1];
      s1a += q[e] * k1[e];
      s1b += q[e + 1] * k1[e + 1];
    }
    float s0 = s0a + s0b, s1 = s1a + s1b;
    // increasing ball index, strict > : keeps lowest index on ties (lax.top_k)
    if (s0 > v0) { v1 = v0; i1 = i0; v0 = s0; i0 = b; }
    else if (s0 > v1) { v1 = s0; i1 = b; }
    if (s1 > v0) { v1 = v0; i1 = i0; v0 = s1; i0 = b + 1; }
    else if (s1 > v1) { v1 = s1; i1 = b + 1; }
  }

  topk[(h * NM + t) * 2 + 0] = i0;
  topk[(h * NM + t) * 2 + 1] = i1;
}

// ---------------------------------------------------------------------------
// K4: gather 2 balls' K/V, logits, softmax, weighted-V. One wave per (h,q).
// ---------------------------------------------------------------------------
__global__ __launch_bounds__(64) void k_attn(
    const float* __restrict__ qbuf, const float* __restrict__ kbuf,
    const float* __restrict__ vbuf, const int* __restrict__ topk,
    float* __restrict__ attout) {
  __shared__ float q_s[HE];
  __shared__ float ks[32 * 33];
  __shared__ float vs[32 * 33];
  __shared__ float attw[32];
  int pair = blockIdx.x;
  int h = pair >> 13, t = pair & (NM - 1);
  int tid = threadIdx.x;
  int b0 = topk[(h * NM + t) * 2 + 0];
  int b1 = topk[(h * NM + t) * 2 + 1];
  if (tid < HE) q_s[tid] = qbuf[(h * NM + t) * HE + tid];
#pragma unroll
  for (int i = 0; i < 16; ++i) {
    int p = tid + 64 * i;  // 0..1023
    int j = p >> 5, e = p & 31;
    int ball = (j < 16) ? b0 : b1;
    int m = j & 15;
    int src = (h * NM + ball * BALL + m) * HE + e;
    ks[j * 33 + e] = kbuf[src];
    vs[j * 33 + e] = vbuf[src];
  }
  __syncthreads();
  int j = tid & 31, half = tid >> 5;
  int e0 = half * 16;
  float partial = 0.f;
#pragma unroll
  for (int e = 0; e < 16; ++e) partial += q_s[e0 + e] * ks[j * 33 + e0 + e];
  partial += __shfl_xor(partial, 32);
  float logit = partial * 0.17677669529663687f;  // 1/sqrt(32)
  float mx = logit;
#pragma unroll
  for (int mk = 1; mk <= 16; mk <<= 1) mx = fmaxf(mx, __shfl_xor(mx, mk));
  float pexp = __expf(logit - mx);
  float sum = pexp;
#pragma unroll
  for (int mk = 1; mk <= 16; mk <<= 1) sum += __shfl_xor(sum, mk);
  float attn = pexp / sum;
  if (tid < 32) attw[j] = attn;
  __syncthreads();
  int e = tid & 31, j0 = half * 16;
  float po = 0.f;
#pragma unroll
  for (int jj = 0; jj < 16; ++jj) po += attw[j0 + jj] * vs[(j0 + jj) * 33 + e];
  po += __shfl_xor(po, 32);
  if (tid < 32) attout[t * DIM + h * HE + e] = po;
}

// K5: out = attout @ W_proj^T + b_proj  (same tiling as K2, dense output)
__global__ __launch_bounds__(256) void k_proj(
    const float* __restrict__ A, const float* __restrict__ B,
    const float* __restrict__ bias, float* __restrict__ out) {
  __shared__ float As[BK][LDP];
  __shared__ float Bs[BK][LDP];
  int tid = threadIdx.x;
  int m0 = blockIdx.x * BM;
  int n0 = blockIdx.y * BN;
  int lr = tid >> 2;
  int lk = (tid & 3) * 4;
  int tx = tid & 15, ty = tid >> 4;
  float acc[4][4] = {};
  for (int k0 = 0; k0 < DIM; k0 += BK) {
    float4 av = *(const float4*)&A[(m0 + lr) * DIM + k0 + lk];
    float4 bv = *(const float4*)&B[(n0 + lr) * DIM + k0 + lk];
    As[lk + 0][lr] = av.x; As[lk + 1][lr] = av.y;
    As[lk + 2][lr] = av.z; As[lk + 3][lr] = av.w;
    Bs[lk + 0][lr] = bv.x; Bs[lk + 1][lr] = bv.y;
    Bs[lk + 2][lr] = bv.z; Bs[lk + 3][lr] = bv.w;
    __syncthreads();
#pragma unroll
    for (int k = 0; k < BK; ++k) {
      float4 a = *(const float4*)&As[k][ty * 4];
      float4 b = *(const float4*)&Bs[k][tx * 4];
      float ar[4] = {a.x, a.y, a.z, a.w};
      float br[4] = {b.x, b.y, b.z, b.w};
#pragma unroll
      for (int i = 0; i < 4; ++i)
#pragma unroll
        for (int j = 0; j < 4; ++j) acc[i][j] += ar[i] * br[j];
    }
    __syncthreads();
  }
#pragma unroll
  for (int i = 0; i < 4; ++i) {
    int t = m0 + ty * 4 + i;
#pragma unroll
    for (int j = 0; j < 4; ++j) {
      int o = n0 + tx * 4 + j;
      out[t * DIM + o] = acc[i][j] + bias[o];
    }
  }
}

extern "C" void kernel_launch(void* const* d_in, const int* in_sizes, int n_in,
                              void* d_out, int out_size, void* d_ws,
                              size_t ws_size, hipStream_t stream) {
  const float* x = (const float*)d_in[0];
  const float* pos = (const float*)d_in[1];
  const float* Wqkv = (const float*)d_in[2];
  const float* bqkv = (const float*)d_in[3];
  const float* Wpe = (const float*)d_in[4];
  const float* bpe = (const float*)d_in[5];
  const float* Wproj = (const float*)d_in[6];
  const float* bproj = (const float*)d_in[7];
  float* out = (float*)d_out;

  float* ws = (float*)d_ws;
  float* xp = ws;                          // NM*DIM
  float* qbuf = xp + NM * DIM;             // NH*NM*HE
  float* kbuf = qbuf + NH * NM * HE;       // NH*NM*HE
  float* vbuf = kbuf + NH * NM * HE;       // NH*NM*HE
  float* kmean = vbuf + NH * NM * HE;      // NH*NBALLS*HE
  int* topk = (int*)(kmean + NH * NBALLS * HE);  // NH*NM*2 ints
  float* attout = (float*)(topk + NH * NM * 2);  // NM*DIM

  k_posembed<<<NBALLS, 256, 0, stream>>>(x, pos, Wpe, bpe, xp);
  k_qkv_gemm<<<dim3(NM / BM, 768 / BN), 256, 0, stream>>>(xp, Wqkv, bqkv,
                                                          qbuf, kbuf, vbuf);
  k_kmean<<<(NH * NBALLS) / 8, 256, 0, stream>>>(kbuf, kmean);
  k_sim_topk<<<dim3(NM / 256, NH), 256, 0, stream>>>(qbuf, kmean, topk);
  k_attn<<<NH * NM, 64, 0, stream>>>(qbuf, kbuf, vbuf, topk, attout);
  k_proj<<<dim3(NM / BM, DIM / BN), 256, 0, stream>>>(attout, Wproj, bproj,
                                                      out);
}

// Round 4
// 278.664 us; speedup vs baseline: 1.1766x; 1.1766x over previous
//
#include <hip/hip_runtime.h>

#define DIM 256
#define NH 8
#define HE 32          // head dim E
#define BALL 16        // ball size M
#define NBALLS 512
#define NM 8192
#define SCH 4          // sim ball chunks
#define CHB (NBALLS / SCH)  // 128 balls per chunk

// ---------------------------------------------------------------------------
// K1: x' = x + rel @ W_pe^T + b_pe, rel = pos - per-ball mean(pos)
// ---------------------------------------------------------------------------
__global__ __launch_bounds__(256) void k_posembed(
    const float* __restrict__ x, const float* __restrict__ pos,
    const float* __restrict__ Wpe, const float* __restrict__ bpe,
    float* __restrict__ xp) {
  __shared__ float ps[BALL * 3];
  __shared__ float mean_s[3];
  int ball = blockIdx.x;
  int tid = threadIdx.x;
  if (tid < BALL * 3) ps[tid] = pos[ball * BALL * 3 + tid];
  __syncthreads();
  if (tid < 3) {
    float s = 0.f;
    for (int m = 0; m < BALL; ++m) s += ps[m * 3 + tid];
    mean_s[tid] = s * (1.f / BALL);
  }
  __syncthreads();
  int d = tid;
  float w0 = Wpe[d * 3 + 0], w1 = Wpe[d * 3 + 1], w2 = Wpe[d * 3 + 2];
  float bp = bpe[d];
  float m0 = mean_s[0], m1 = mean_s[1], m2 = mean_s[2];
  for (int m = 0; m < BALL; ++m) {
    int t = ball * BALL + m;
    float r0 = ps[m * 3 + 0] - m0;
    float r1 = ps[m * 3 + 1] - m1;
    float r2 = ps[m * 3 + 2] - m2;
    xp[t * DIM + d] = x[t * DIM + d] + r0 * w0 + r1 * w1 + r2 * w2 + bp;
  }
}

// ---------------------------------------------------------------------------
// fp32 tiled GEMM: BM=BN=64, BK=16, 64 threads/block (1 wave), 8x8 microtile.
// 4 ds_read_b128 per 64 FMAs (2x better LDS ratio than 4x4 microtile).
// ---------------------------------------------------------------------------
#define BK 16
#define LDP 68  // +4 pad: 2-way LDS aliasing max (free on CDNA4)

// K2: qkv = x' @ W_qkv^T + b_qkv, scattered to q/k/v buffers.
// output column o = h*96 + e*3 + c (c: 0=q,1=k,2=v), dest layout [H][nm][E]
__global__ __launch_bounds__(64) void k_qkv_gemm(
    const float* __restrict__ A, const float* __restrict__ B,
    const float* __restrict__ bias,
    float* __restrict__ qbuf, float* __restrict__ kbuf,
    float* __restrict__ vbuf) {
  __shared__ float As[BK][LDP];
  __shared__ float Bs[BK][LDP];
  int tid = threadIdx.x;  // 0..63
  int m0 = blockIdx.x * 64;
  int n0 = blockIdx.y * 64;
  int lr = tid >> 2;        // 0..15
  int lk = (tid & 3) * 4;   // 0,4,8,12
  int tx = tid & 7, ty = tid >> 3;
  float acc[8][8] = {};
  for (int k0 = 0; k0 < DIM; k0 += BK) {
#pragma unroll
    for (int i = 0; i < 4; ++i) {
      int r = lr + 16 * i;
      float4 av = *(const float4*)&A[(m0 + r) * DIM + k0 + lk];
      float4 bv = *(const float4*)&B[(n0 + r) * DIM + k0 + lk];
      As[lk + 0][r] = av.x; As[lk + 1][r] = av.y;
      As[lk + 2][r] = av.z; As[lk + 3][r] = av.w;
      Bs[lk + 0][r] = bv.x; Bs[lk + 1][r] = bv.y;
      Bs[lk + 2][r] = bv.z; Bs[lk + 3][r] = bv.w;
    }
    __syncthreads();
#pragma unroll
    for (int k = 0; k < BK; ++k) {
      float a[8], b[8];
      *(float4*)&a[0] = *(const float4*)&As[k][ty * 8];
      *(float4*)&a[4] = *(const float4*)&As[k][ty * 8 + 4];
      *(float4*)&b[0] = *(const float4*)&Bs[k][tx * 8];
      *(float4*)&b[4] = *(const float4*)&Bs[k][tx * 8 + 4];
#pragma unroll
      for (int i = 0; i < 8; ++i)
#pragma unroll
        for (int j = 0; j < 8; ++j) acc[i][j] += a[i] * b[j];
    }
    __syncthreads();
  }
#pragma unroll
  for (int i = 0; i < 8; ++i) {
    int t = m0 + ty * 8 + i;
#pragma unroll
    for (int j = 0; j < 8; ++j) {
      int o = n0 + tx * 8 + j;
      float val = acc[i][j] + bias[o];
      int c = o % 3;
      int r = o / 3;          // h*32 + e
      int e = r & 31, h = r >> 5;
      float* dst = (c == 0) ? qbuf : (c == 1) ? kbuf : vbuf;
      dst[(h * NM + t) * HE + e] = val;
    }
  }
}

// K2b: kmean[h][ball][e] = mean over m of kbuf[h][ball*16+m][e]
__global__ __launch_bounds__(256) void k_kmean(
    const float* __restrict__ kbuf, float* __restrict__ kmean) {
  int tid = threadIdx.x;
  int gb = blockIdx.x * 8 + (tid >> 5);  // h*512 + ball
  int e = tid & 31;
  int h = gb >> 9, ball = gb & 511;
  float s = 0.f;
#pragma unroll
  for (int m = 0; m < BALL; ++m)
    s += kbuf[(h * NM + ball * BALL + m) * HE + e];
  kmean[gb * HE + e] = s * (1.f / BALL);
}

// ---------------------------------------------------------------------------
// K3 v4: one thread = one query, scans CHB=128 balls (chunk = blockIdx.z).
// 4 chunks -> 4 waves/SIMD TLP. q held in 8 explicit float4 registers (no
// array -> no scratch spill). kmean loads are wave-uniform -> scalar path.
// Partial top2 per (chunk,h,t) written as one float4; merged in k_attn.
// ---------------------------------------------------------------------------
#define DOT8(sa, sb, qa, qb, ka, kb)            \
  sa += qa.x * ka.x; sb += qa.y * ka.y;         \
  sa += qa.z * ka.z; sb += qa.w * ka.w;         \
  sa += qb.x * kb.x; sb += qb.y * kb.y;         \
  sa += qb.z * kb.z; sb += qb.w * kb.w;

__global__ __launch_bounds__(256, 4) void k_sim_topk(
    const float* __restrict__ qbuf, const float* __restrict__ kmean,
    float4* __restrict__ pws) {
  int h = blockIdx.y;
  int chunk = blockIdx.z;
  int t = blockIdx.x * 256 + threadIdx.x;

  const float4* qp = (const float4*)&qbuf[(h * NM + t) * HE];
  float4 q0 = qp[0], q1 = qp[1], q2 = qp[2], q3 = qp[3];
  float4 q4 = qp[4], q5 = qp[5], q6 = qp[6], q7 = qp[7];

  const float* __restrict__ km = kmean + (h * NBALLS + chunk * CHB) * HE;
  float v0 = -1e30f, v1 = -1e30f;
  int i0 = chunk * CHB, i1 = chunk * CHB;

#pragma unroll 2
  for (int b = 0; b < CHB; b += 2) {
    const float4* kp = (const float4*)(km + b * HE);
    float s0a = 0.f, s0b = 0.f, s1a = 0.f, s1b = 0.f;
    {
      float4 ka = kp[0], kb = kp[1];
      DOT8(s0a, s0b, q0, q1, ka, kb);
      ka = kp[2]; kb = kp[3];
      DOT8(s0a, s0b, q2, q3, ka, kb);
      ka = kp[4]; kb = kp[5];
      DOT8(s0a, s0b, q4, q5, ka, kb);
      ka = kp[6]; kb = kp[7];
      DOT8(s0a, s0b, q6, q7, ka, kb);
    }
    {
      float4 ka = kp[8], kb = kp[9];
      DOT8(s1a, s1b, q0, q1, ka, kb);
      ka = kp[10]; kb = kp[11];
      DOT8(s1a, s1b, q2, q3, ka, kb);
      ka = kp[12]; kb = kp[13];
      DOT8(s1a, s1b, q4, q5, ka, kb);
      ka = kp[14]; kb = kp[15];
      DOT8(s1a, s1b, q6, q7, ka, kb);
    }
    float s0 = s0a + s0b, s1 = s1a + s1b;
    int gb = chunk * CHB + b;
    // increasing ball index, strict > : keeps lowest index on ties
    if (s0 > v0) { v1 = v0; i1 = i0; v0 = s0; i0 = gb; }
    else if (s0 > v1) { v1 = s0; i1 = gb; }
    if (s1 > v0) { v1 = v0; i1 = i0; v0 = s1; i0 = gb + 1; }
    else if (s1 > v1) { v1 = s1; i1 = gb + 1; }
  }

  pws[(chunk * NH + h) * NM + t] =
      make_float4(v0, __int_as_float(i0), v1, __int_as_float(i1));
}

// ---------------------------------------------------------------------------
// K4: merge 4 partial top2 -> (b0,b1); gather K/V, softmax, weighted-V.
// One wave per (h,q).
// ---------------------------------------------------------------------------
__device__ __forceinline__ void merge_top2(float& v0, int& i0, float& v1,
                                           int& i1, float w0, int j0,
                                           float w1, int j1) {
  if (w0 > v0) {
    float tv; int ti;
    tv = v0; v0 = w0; w0 = tv; ti = i0; i0 = j0; j0 = ti;
    tv = v1; v1 = w1; w1 = tv; ti = i1; i1 = j1; j1 = ti;
  }
  if (w0 > v1) { v1 = w0; i1 = j0; }
}

__global__ __launch_bounds__(64) void k_attn(
    const float* __restrict__ qbuf, const float* __restrict__ kbuf,
    const float* __restrict__ vbuf, const float4* __restrict__ pws,
    float* __restrict__ attout) {
  __shared__ float q_s[HE];
  __shared__ float ks[32 * 33];
  __shared__ float vs[32 * 33];
  __shared__ float attw[32];
  int pair = blockIdx.x;
  int h = pair >> 13, t = pair & (NM - 1);
  int tid = threadIdx.x;

  // merge the 4 chunk partials (chunk order preserves lowest-index ties)
  float4 p = pws[(0 * NH + h) * NM + t];
  float v0 = p.x, v1 = p.z;
  int b0 = __float_as_int(p.y), b1 = __float_as_int(p.w);
#pragma unroll
  for (int c = 1; c < SCH; ++c) {
    p = pws[(c * NH + h) * NM + t];
    merge_top2(v0, b0, v1, b1, p.x, __float_as_int(p.y), p.z,
               __float_as_int(p.w));
  }

  if (tid < HE) q_s[tid] = qbuf[(h * NM + t) * HE + tid];
#pragma unroll
  for (int i = 0; i < 16; ++i) {
    int pidx = tid + 64 * i;  // 0..1023
    int j = pidx >> 5, e = pidx & 31;
    int ball = (j < 16) ? b0 : b1;
    int m = j & 15;
    int src = (h * NM + ball * BALL + m) * HE + e;
    ks[j * 33 + e] = kbuf[src];
    vs[j * 33 + e] = vbuf[src];
  }
  __syncthreads();
  int j = tid & 31, half = tid >> 5;
  int e0 = half * 16;
  float partial = 0.f;
#pragma unroll
  for (int e = 0; e < 16; ++e) partial += q_s[e0 + e] * ks[j * 33 + e0 + e];
  partial += __shfl_xor(partial, 32);
  float logit = partial * 0.17677669529663687f;  // 1/sqrt(32)
  float mx = logit;
#pragma unroll
  for (int mk = 1; mk <= 16; mk <<= 1) mx = fmaxf(mx, __shfl_xor(mx, mk));
  float pexp = __expf(logit - mx);
  float sum = pexp;
#pragma unroll
  for (int mk = 1; mk <= 16; mk <<= 1) sum += __shfl_xor(sum, mk);
  float attn = pexp / sum;
  if (tid < 32) attw[j] = attn;
  __syncthreads();
  int e = tid & 31, j0 = half * 16;
  float po = 0.f;
#pragma unroll
  for (int jj = 0; jj < 16; ++jj) po += attw[j0 + jj] * vs[(j0 + jj) * 33 + e];
  po += __shfl_xor(po, 32);
  if (tid < 32) attout[t * DIM + h * HE + e] = po;
}

// K5: out = attout @ W_proj^T + b_proj (same 8x8 structure, dense output)
__global__ __launch_bounds__(64) void k_proj(
    const float* __restrict__ A, const float* __restrict__ B,
    const float* __restrict__ bias, float* __restrict__ out) {
  __shared__ float As[BK][LDP];
  __shared__ float Bs[BK][LDP];
  int tid = threadIdx.x;
  int m0 = blockIdx.x * 64;
  int n0 = blockIdx.y * 64;
  int lr = tid >> 2;
  int lk = (tid & 3) * 4;
  int tx = tid & 7, ty = tid >> 3;
  float acc[8][8] = {};
  for (int k0 = 0; k0 < DIM; k0 += BK) {
#pragma unroll
    for (int i = 0; i < 4; ++i) {
      int r = lr + 16 * i;
      float4 av = *(const float4*)&A[(m0 + r) * DIM + k0 + lk];
      float4 bv = *(const float4*)&B[(n0 + r) * DIM + k0 + lk];
      As[lk + 0][r] = av.x; As[lk + 1][r] = av.y;
      As[lk + 2][r] = av.z; As[lk + 3][r] = av.w;
      Bs[lk + 0][r] = bv.x; Bs[lk + 1][r] = bv.y;
      Bs[lk + 2][r] = bv.z; Bs[lk + 3][r] = bv.w;
    }
    __syncthreads();
#pragma unroll
    for (int k = 0; k < BK; ++k) {
      float a[8], b[8];
      *(float4*)&a[0] = *(const float4*)&As[k][ty * 8];
      *(float4*)&a[4] = *(const float4*)&As[k][ty * 8 + 4];
      *(float4*)&b[0] = *(const float4*)&Bs[k][tx * 8];
      *(float4*)&b[4] = *(const float4*)&Bs[k][tx * 8 + 4];
#pragma unroll
      for (int i = 0; i < 8; ++i)
#pragma unroll
        for (int j = 0; j < 8; ++j) acc[i][j] += a[i] * b[j];
    }
    __syncthreads();
  }
#pragma unroll
  for (int i = 0; i < 8; ++i) {
    int t = m0 + ty * 8 + i;
#pragma unroll
    for (int j = 0; j < 8; ++j) {
      int o = n0 + tx * 8 + j;
      out[t * DIM + o] = acc[i][j] + bias[o];
    }
  }
}

extern "C" void kernel_launch(void* const* d_in, const int* in_sizes, int n_in,
                              void* d_out, int out_size, void* d_ws,
                              size_t ws_size, hipStream_t stream) {
  const float* x = (const float*)d_in[0];
  const float* pos = (const float*)d_in[1];
  const float* Wqkv = (const float*)d_in[2];
  const float* bqkv = (const float*)d_in[3];
  const float* Wpe = (const float*)d_in[4];
  const float* bpe = (const float*)d_in[5];
  const float* Wproj = (const float*)d_in[6];
  const float* bproj = (const float*)d_in[7];
  float* out = (float*)d_out;

  float* ws = (float*)d_ws;
  float* xp = ws;                          // NM*DIM (dead after k_qkv_gemm)
  float* qbuf = xp + NM * DIM;             // NH*NM*HE
  float* kbuf = qbuf + NH * NM * HE;       // NH*NM*HE
  float* vbuf = kbuf + NH * NM * HE;       // NH*NM*HE
  float* kmean = vbuf + NH * NM * HE;      // NH*NBALLS*HE
  float* attout = kmean + NH * NBALLS * HE;  // NM*DIM
  float4* pws = (float4*)xp;  // aliases xp: SCH*NH*NM float4 = 2MB (< 8MB)

  k_posembed<<<NBALLS, 256, 0, stream>>>(x, pos, Wpe, bpe, xp);
  k_qkv_gemm<<<dim3(NM / 64, 768 / 64), 64, 0, stream>>>(xp, Wqkv, bqkv,
                                                         qbuf, kbuf, vbuf);
  k_kmean<<<(NH * NBALLS) / 8, 256, 0, stream>>>(kbuf, kmean);
  k_sim_topk<<<dim3(NM / 256, NH, SCH), 256, 0, stream>>>(qbuf, kmean, pws);
  k_attn<<<NH * NM, 64, 0, stream>>>(qbuf, kbuf, vbuf, pws, attout);
  k_proj<<<dim3(NM / 64, DIM / 64), 64, 0, stream>>>(attout, Wproj, bproj,
                                                     out);
}

// Round 7
// 221.445 us; speedup vs baseline: 1.4807x; 1.2584x over previous
//
#include <hip/hip_runtime.h>

#define DIM 256
#define NH 8
#define HE 32          // head dim E
#define BALL 16        // ball size M
#define NBALLS 512
#define NM 8192
#define SCH 4          // sim ball chunks
#define CHB (NBALLS / SCH)  // 128 balls per chunk

typedef _Float16 f16x8 __attribute__((ext_vector_type(8)));
typedef float f32x4 __attribute__((ext_vector_type(4)));

// fp16 2-term split: x = hi + lo, |x - hi - lo| <= 2^-24 |x| (fp32-quality)
__device__ __forceinline__ void f2h_split(float val, _Float16& hi,
                                          _Float16& lo) {
  hi = (_Float16)val;
  lo = (_Float16)(val - (float)hi);
}

// ---------------------------------------------------------------------------
// K1: x' = x + rel @ W_pe^T + b_pe; emit hi/lo fp16 into xcat[t][0:256|256:512]
// ---------------------------------------------------------------------------
__global__ __launch_bounds__(256) void k_posembed(
    const float* __restrict__ x, const float* __restrict__ pos,
    const float* __restrict__ Wpe, const float* __restrict__ bpe,
    _Float16* __restrict__ xcat) {
  __shared__ float ps[BALL * 3];
  __shared__ float mean_s[3];
  int ball = blockIdx.x;
  int tid = threadIdx.x;
  if (tid < BALL * 3) ps[tid] = pos[ball * BALL * 3 + tid];
  __syncthreads();
  if (tid < 3) {
    float s = 0.f;
    for (int m = 0; m < BALL; ++m) s += ps[m * 3 + tid];
    mean_s[tid] = s * (1.f / BALL);
  }
  __syncthreads();
  int d = tid;
  float w0 = Wpe[d * 3 + 0], w1 = Wpe[d * 3 + 1], w2 = Wpe[d * 3 + 2];
  float bp = bpe[d];
  float m0 = mean_s[0], m1 = mean_s[1], m2 = mean_s[2];
  for (int m = 0; m < BALL; ++m) {
    int t = ball * BALL + m;
    float r0 = ps[m * 3 + 0] - m0;
    float r1 = ps[m * 3 + 1] - m1;
    float r2 = ps[m * 3 + 2] - m2;
    float val = x[t * DIM + d] + r0 * w0 + r1 * w1 + r2 * w2 + bp;
    _Float16 hi, lo;
    f2h_split(val, hi, lo);
    xcat[t * 512 + d] = hi;
    xcat[t * 512 + 256 + d] = lo;
  }
}

// ---------------------------------------------------------------------------
// K1b: split weights into concatenated-K fp16 form.
// B layout [N][768]: cols 0:256 = hi, 256:512 = hi (dup), 512:768 = lo
// (pairs with A segments [hi | lo | hi] -> hihi + lohi + hilo)
// ---------------------------------------------------------------------------
__global__ __launch_bounds__(256) void k_wsplit(
    const float* __restrict__ Wq, const float* __restrict__ Wp,
    _Float16* __restrict__ Bq, _Float16* __restrict__ Bp) {
  int n = blockIdx.x, k = threadIdx.x;
  if (n < 768) {
    _Float16 hi, lo;
    f2h_split(Wq[n * 256 + k], hi, lo);
    Bq[n * 768 + k] = hi;
    Bq[n * 768 + 256 + k] = hi;
    Bq[n * 768 + 512 + k] = lo;
  } else {
    int r = n - 768;
    _Float16 hi, lo;
    f2h_split(Wp[r * 256 + k], hi, lo);
    Bp[r * 768 + k] = hi;
    Bp[r * 768 + 256 + k] = hi;
    Bp[r * 768 + 512 + k] = lo;
  }
}

// ---------------------------------------------------------------------------
// Split-fp16 MFMA GEMM: C[M,N] = Acat[M,512(hi|lo)] x Bcat[N,768]^T in fp32.
// Logical K=768; A's third segment re-reads its hi columns (ak0 remap).
// 256 thr, tile 128x64, BK=64, wave-tile 64x32 = 4x2 mfma_f32_16x16x32_f16.
// LDS rows padded to 72 fp16 (2-way bank aliasing only = free on CDNA4).
// Epilogue: functor(row, col, val).
// ---------------------------------------------------------------------------
#define TBK 64
#define LDA 72

template <typename Epi>
__device__ __forceinline__ void gemm_main(const _Float16* __restrict__ A,
                                          const _Float16* __restrict__ B,
                                          const float* __restrict__ bias,
                                          Epi epi) {
  __shared__ _Float16 As[128 * LDA];
  __shared__ _Float16 Bs[64 * LDA];
  int tid = threadIdx.x;
  int m0 = blockIdx.x * 128;
  int n0 = blockIdx.y * 64;
  int w = tid >> 6, lane = tid & 63;
  int wm = (w >> 1) * 64, wn = (w & 1) * 32;
  int l15 = lane & 15, quad = lane >> 4;
  f32x4 acc[4][2] = {};
  for (int k0 = 0; k0 < 768; k0 += TBK) {
    int ak0 = (k0 < 512) ? k0 : (k0 - 512);
    if (k0) __syncthreads();
#pragma unroll
    for (int t = 0; t < 4; ++t) {
      int f = tid + 256 * t;
      int row = f >> 3, seg = f & 7;
      *(uint4*)&As[row * LDA + seg * 8] =
          *(const uint4*)&A[(m0 + row) * 512 + ak0 + seg * 8];
    }
#pragma unroll
    for (int t = 0; t < 2; ++t) {
      int f = tid + 256 * t;
      int row = f >> 3, seg = f & 7;
      *(uint4*)&Bs[row * LDA + seg * 8] =
          *(const uint4*)&B[(n0 + row) * 768 + k0 + seg * 8];
    }
    __syncthreads();
#pragma unroll
    for (int kk = 0; kk < TBK; kk += 32) {
      f16x8 bfr0 = *(const f16x8*)&Bs[(wn + l15) * LDA + kk + quad * 8];
      f16x8 bfr1 = *(const f16x8*)&Bs[(wn + 16 + l15) * LDA + kk + quad * 8];
#pragma unroll
      for (int mt = 0; mt < 4; ++mt) {
        f16x8 afr =
            *(const f16x8*)&As[(wm + mt * 16 + l15) * LDA + kk + quad * 8];
        acc[mt][0] = __builtin_amdgcn_mfma_f32_16x16x32_f16(afr, bfr0,
                                                            acc[mt][0], 0, 0,
                                                            0);
        acc[mt][1] = __builtin_amdgcn_mfma_f32_16x16x32_f16(afr, bfr1,
                                                            acc[mt][1], 0, 0,
                                                            0);
      }
    }
  }
#pragma unroll
  for (int mt = 0; mt < 4; ++mt) {
#pragma unroll
    for (int nt = 0; nt < 2; ++nt) {
      int col = n0 + wn + nt * 16 + l15;
      float bv = bias[col];
#pragma unroll
      for (int r = 0; r < 4; ++r) {
        int row = m0 + wm + mt * 16 + quad * 4 + r;
        epi(row, col, acc[mt][nt][r] + bv);
      }
    }
  }
}

// K2: qkv GEMM, scatter col o = h*96+e*3+c to q/k/v [H][nm][E]
__global__ __launch_bounds__(256) void k_qkv_gemm(
    const _Float16* __restrict__ A, const _Float16* __restrict__ B,
    const float* __restrict__ bias, float* __restrict__ qbuf,
    float* __restrict__ kbuf, float* __restrict__ vbuf) {
  gemm_main(A, B, bias, [=](int row, int col, float val) {
    int c = col % 3;
    int rr = col / 3;
    int e = rr & 31;
    int h = rr >> 5;
    float* dst = (c == 0) ? qbuf : (c == 1) ? kbuf : vbuf;
    dst[(h * NM + row) * HE + e] = val;
  });
}

// K5: proj GEMM, dense output
__global__ __launch_bounds__(256) void k_proj(
    const _Float16* __restrict__ A, const _Float16* __restrict__ B,
    const float* __restrict__ bias, float* __restrict__ out) {
  gemm_main(A, B, bias,
            [=](int row, int col, float val) { out[row * DIM + col] = val; });
}

// K2b: kmean[h][ball][e] = mean over m of kbuf[h][ball*16+m][e]
__global__ __launch_bounds__(256) void k_kmean(
    const float* __restrict__ kbuf, float* __restrict__ kmean) {
  int tid = threadIdx.x;
  int gb = blockIdx.x * 8 + (tid >> 5);  // h*512 + ball
  int e = tid & 31;
  int h = gb >> 9, ball = gb & 511;
  float s = 0.f;
#pragma unroll
  for (int m = 0; m < BALL; ++m)
    s += kbuf[(h * NM + ball * BALL + m) * HE + e];
  kmean[gb * HE + e] = s * (1.f / BALL);
}

// ---------------------------------------------------------------------------
// K3: one thread = one query, scans CHB=128 balls (chunk = blockIdx.z).
// q in 8 explicit float4 regs; kmean wave-uniform -> scalar path.
// Partial top2 per (chunk,h,t) as one float4; merged in k_attn.
// ---------------------------------------------------------------------------
#define DOT8(sa, sb, qa, qb, ka, kb)            \
  sa += qa.x * ka.x; sb += qa.y * ka.y;         \
  sa += qa.z * ka.z; sb += qa.w * ka.w;         \
  sa += qb.x * kb.x; sb += qb.y * kb.y;         \
  sa += qb.z * kb.z; sb += qb.w * kb.w;

__global__ __launch_bounds__(256, 4) void k_sim_topk(
    const float* __restrict__ qbuf, const float* __restrict__ kmean,
    float4* __restrict__ pws) {
  int h = blockIdx.y;
  int chunk = blockIdx.z;
  int t = blockIdx.x * 256 + threadIdx.x;

  const float4* qp = (const float4*)&qbuf[(h * NM + t) * HE];
  float4 q0 = qp[0], q1 = qp[1], q2 = qp[2], q3 = qp[3];
  float4 q4 = qp[4], q5 = qp[5], q6 = qp[6], q7 = qp[7];

  const float* __restrict__ km = kmean + (h * NBALLS + chunk * CHB) * HE;
  float v0 = -1e30f, v1 = -1e30f;
  int i0 = chunk * CHB, i1 = chunk * CHB;

#pragma unroll 2
  for (int b = 0; b < CHB; b += 2) {
    const float4* kp = (const float4*)(km + b * HE);
    float s0a = 0.f, s0b = 0.f, s1a = 0.f, s1b = 0.f;
    {
      float4 ka = kp[0], kb = kp[1];
      DOT8(s0a, s0b, q0, q1, ka, kb);
      ka = kp[2]; kb = kp[3];
      DOT8(s0a, s0b, q2, q3, ka, kb);
      ka = kp[4]; kb = kp[5];
      DOT8(s0a, s0b, q4, q5, ka, kb);
      ka = kp[6]; kb = kp[7];
      DOT8(s0a, s0b, q6, q7, ka, kb);
    }
    {
      float4 ka = kp[8], kb = kp[9];
      DOT8(s1a, s1b, q0, q1, ka, kb);
      ka = kp[10]; kb = kp[11];
      DOT8(s1a, s1b, q2, q3, ka, kb);
      ka = kp[12]; kb = kp[13];
      DOT8(s1a, s1b, q4, q5, ka, kb);
      ka = kp[14]; kb = kp[15];
      DOT8(s1a, s1b, q6, q7, ka, kb);
    }
    float s0 = s0a + s0b, s1 = s1a + s1b;
    int gb = chunk * CHB + b;
    if (s0 > v0) { v1 = v0; i1 = i0; v0 = s0; i0 = gb; }
    else if (s0 > v1) { v1 = s0; i1 = gb; }
    if (s1 > v0) { v1 = v0; i1 = i0; v0 = s1; i0 = gb + 1; }
    else if (s1 > v1) { v1 = s1; i1 = gb + 1; }
  }

  pws[(chunk * NH + h) * NM + t] =
      make_float4(v0, __int_as_float(i0), v1, __int_as_float(i1));
}

// ---------------------------------------------------------------------------
// K4: merge 4 partial top2 -> (b0,b1); gather K/V, softmax, weighted-V.
// One wave per (h,q). Output emitted as hi/lo fp16 into acat (for proj GEMM).
// ---------------------------------------------------------------------------
__device__ __forceinline__ void merge_top2(float& v0, int& i0, float& v1,
                                           int& i1, float w0, int j0,
                                           float w1, int j1) {
  if (w0 > v0) {
    float tv; int ti;
    tv = v0; v0 = w0; w0 = tv; ti = i0; i0 = j0; j0 = ti;
    tv = v1; v1 = w1; w1 = tv; ti = i1; i1 = j1; j1 = ti;
  }
  if (w0 > v1) { v1 = w0; i1 = j0; }
}

__global__ __launch_bounds__(64) void k_attn(
    const float* __restrict__ qbuf, const float* __restrict__ kbuf,
    const float* __restrict__ vbuf, const float4* __restrict__ pws,
    _Float16* __restrict__ acat) {
  __shared__ float q_s[HE];
  __shared__ float ks[32 * 33];
  __shared__ float vs[32 * 33];
  __shared__ float attw[32];
  int pair = blockIdx.x;
  int h = pair >> 13, t = pair & (NM - 1);
  int tid = threadIdx.x;

  float4 p = pws[(0 * NH + h) * NM + t];
  float v0 = p.x, v1 = p.z;
  int b0 = __float_as_int(p.y), b1 = __float_as_int(p.w);
#pragma unroll
  for (int c = 1; c < SCH; ++c) {
    p = pws[(c * NH + h) * NM + t];
    merge_top2(v0, b0, v1, b1, p.x, __float_as_int(p.y), p.z,
               __float_as_int(p.w));
  }

  if (tid < HE) q_s[tid] = qbuf[(h * NM + t) * HE + tid];
#pragma unroll
  for (int i = 0; i < 16; ++i) {
    int pidx = tid + 64 * i;  // 0..1023
    int j = pidx >> 5, e = pidx & 31;
    int ball = (j < 16) ? b0 : b1;
    int m = j & 15;
    int src = (h * NM + ball * BALL + m) * HE + e;
    ks[j * 33 + e] = kbuf[src];
    vs[j * 33 + e] = vbuf[src];
  }
  __syncthreads();
  int j = tid & 31, half = tid >> 5;
  int e0 = half * 16;
  float partial = 0.f;
#pragma unroll
  for (int e = 0; e < 16; ++e) partial += q_s[e0 + e] * ks[j * 33 + e0 + e];
  partial += __shfl_xor(partial, 32);
  float logit = partial * 0.17677669529663687f;  // 1/sqrt(32)
  float mx = logit;
#pragma unroll
  for (int mk = 1; mk <= 16; mk <<= 1) mx = fmaxf(mx, __shfl_xor(mx, mk));
  float pexp = __expf(logit - mx);
  float sum = pexp;
#pragma unroll
  for (int mk = 1; mk <= 16; mk <<= 1) sum += __shfl_xor(sum, mk);
  float attn = pexp / sum;
  if (tid < 32) attw[j] = attn;
  __syncthreads();
  int e = tid & 31, j0 = half * 16;
  float po = 0.f;
#pragma unroll
  for (int jj = 0; jj < 16; ++jj) po += attw[j0 + jj] * vs[(j0 + jj) * 33 + e];
  po += __shfl_xor(po, 32);
  if (tid < 32) {
    _Float16 hi, lo;
    f2h_split(po, hi, lo);
    acat[t * 512 + h * HE + e] = hi;
    acat[t * 512 + 256 + h * HE + e] = lo;
  }
}

extern "C" void kernel_launch(void* const* d_in, const int* in_sizes, int n_in,
                              void* d_out, int out_size, void* d_ws,
                              size_t ws_size, hipStream_t stream) {
  const float* x = (const float*)d_in[0];
  const float* pos = (const float*)d_in[1];
  const float* Wqkv = (const float*)d_in[2];
  const float* bqkv = (const float*)d_in[3];
  const float* Wpe = (const float*)d_in[4];
  const float* bpe = (const float*)d_in[5];
  const float* Wproj = (const float*)d_in[6];
  const float* bproj = (const float*)d_in[7];
  float* out = (float*)d_out;

  float* qbuf = (float*)d_ws;                    // 8 MB
  float* kbuf = qbuf + NH * NM * HE;             // 8 MB
  float* vbuf = kbuf + NH * NM * HE;             // 8 MB
  float* kmean = vbuf + NH * NM * HE;            // 512 KB
  float4* pws = (float4*)(kmean + NH * NBALLS * HE);  // 4 MB
  _Float16* xcat = (_Float16*)(pws + SCH * NH * NM);  // 8 MB
  _Float16* acat = xcat;  // alias: xcat dead after k_qkv_gemm
  _Float16* Bq = xcat + NM * 512;                // 1.2 MB
  _Float16* Bp = Bq + 768 * 768;                 // 0.4 MB

  k_posembed<<<NBALLS, 256, 0, stream>>>(x, pos, Wpe, bpe, xcat);
  k_wsplit<<<1024, 256, 0, stream>>>(Wqkv, Wproj, Bq, Bp);
  k_qkv_gemm<<<dim3(NM / 128, 768 / 64), 256, 0, stream>>>(xcat, Bq, bqkv,
                                                           qbuf, kbuf, vbuf);
  k_kmean<<<(NH * NBALLS) / 8, 256, 0, stream>>>(kbuf, kmean);
  k_sim_topk<<<dim3(NM / 256, NH, SCH), 256, 0, stream>>>(qbuf, kmean, pws);
  k_attn<<<NH * NM, 64, 0, stream>>>(qbuf, kbuf, vbuf, pws, acat);
  k_proj<<<dim3(NM / 128, DIM / 64), 256, 0, stream>>>(acat, Bp, bproj, out);
}

// Round 8
// 198.245 us; speedup vs baseline: 1.6539x; 1.1170x over previous
//
#include <hip/hip_runtime.h>

#define DIM 256
#define NH 8
#define HE 32          // head dim E
#define BALL 16        // ball size M
#define NBALLS 512
#define NM 8192

typedef _Float16 f16x8 __attribute__((ext_vector_type(8)));
typedef float f32x4 __attribute__((ext_vector_type(4)));

// fp16 2-term split: x = hi + lo, residual ~2^-24 |x| (fp32-quality)
__device__ __forceinline__ void f2h_split(float val, _Float16& hi,
                                          _Float16& lo) {
  hi = (_Float16)val;
  lo = (_Float16)(val - (float)hi);
}

__device__ __forceinline__ void merge_top2(float& v0, int& i0, float& v1,
                                           int& i1, float w0, int j0,
                                           float w1, int j1) {
  if (w0 > v0) {
    float tv; int ti;
    tv = v0; v0 = w0; w0 = tv; ti = i0; i0 = j0; j0 = ti;
    tv = v1; v1 = w1; w1 = tv; ti = i1; i1 = j1; j1 = ti;
  }
  if (w0 > v1) { v1 = w0; i1 = j0; }
}

// ---------------------------------------------------------------------------
// K1: x' = x + rel @ W_pe^T + b_pe; emit hi/lo fp16 into xcat[t][0:256|256:512]
// ---------------------------------------------------------------------------
__global__ __launch_bounds__(256) void k_posembed(
    const float* __restrict__ x, const float* __restrict__ pos,
    const float* __restrict__ Wpe, const float* __restrict__ bpe,
    _Float16* __restrict__ xcat) {
  __shared__ float ps[BALL * 3];
  __shared__ float mean_s[3];
  int ball = blockIdx.x;
  int tid = threadIdx.x;
  if (tid < BALL * 3) ps[tid] = pos[ball * BALL * 3 + tid];
  __syncthreads();
  if (tid < 3) {
    float s = 0.f;
    for (int m = 0; m < BALL; ++m) s += ps[m * 3 + tid];
    mean_s[tid] = s * (1.f / BALL);
  }
  __syncthreads();
  int d = tid;
  float w0 = Wpe[d * 3 + 0], w1 = Wpe[d * 3 + 1], w2 = Wpe[d * 3 + 2];
  float bp = bpe[d];
  float m0 = mean_s[0], m1 = mean_s[1], m2 = mean_s[2];
  for (int m = 0; m < BALL; ++m) {
    int t = ball * BALL + m;
    float r0 = ps[m * 3 + 0] - m0;
    float r1 = ps[m * 3 + 1] - m1;
    float r2 = ps[m * 3 + 2] - m2;
    float val = x[t * DIM + d] + r0 * w0 + r1 * w1 + r2 * w2 + bp;
    _Float16 hi, lo;
    f2h_split(val, hi, lo);
    xcat[t * 512 + d] = hi;
    xcat[t * 512 + 256 + d] = lo;
  }
}

// ---------------------------------------------------------------------------
// K1b: split weights into concatenated-K fp16 form.
// B layout [N][768]: cols 0:256 = hi, 256:512 = hi (dup), 512:768 = lo
// ---------------------------------------------------------------------------
__global__ __launch_bounds__(256) void k_wsplit(
    const float* __restrict__ Wq, const float* __restrict__ Wp,
    _Float16* __restrict__ Bq, _Float16* __restrict__ Bp) {
  int n = blockIdx.x, k = threadIdx.x;
  if (n < 768) {
    _Float16 hi, lo;
    f2h_split(Wq[n * 256 + k], hi, lo);
    Bq[n * 768 + k] = hi;
    Bq[n * 768 + 256 + k] = hi;
    Bq[n * 768 + 512 + k] = lo;
  } else {
    int r = n - 768;
    _Float16 hi, lo;
    f2h_split(Wp[r * 256 + k], hi, lo);
    Bp[r * 768 + k] = hi;
    Bp[r * 768 + 256 + k] = hi;
    Bp[r * 768 + 512 + k] = lo;
  }
}

// ---------------------------------------------------------------------------
// Split-fp16 MFMA GEMM (verified layout). Epilogue: functor(row, col, val).
// ---------------------------------------------------------------------------
#define TBK 64
#define LDA 72

template <typename Epi>
__device__ __forceinline__ void gemm_main(const _Float16* __restrict__ A,
                                          const _Float16* __restrict__ B,
                                          const float* __restrict__ bias,
                                          Epi epi) {
  __shared__ _Float16 As[128 * LDA];
  __shared__ _Float16 Bs[64 * LDA];
  int tid = threadIdx.x;
  int m0 = blockIdx.x * 128;
  int n0 = blockIdx.y * 64;
  int w = tid >> 6, lane = tid & 63;
  int wm = (w >> 1) * 64, wn = (w & 1) * 32;
  int l15 = lane & 15, quad = lane >> 4;
  f32x4 acc[4][2] = {};
  for (int k0 = 0; k0 < 768; k0 += TBK) {
    int ak0 = (k0 < 512) ? k0 : (k0 - 512);
    if (k0) __syncthreads();
#pragma unroll
    for (int t = 0; t < 4; ++t) {
      int f = tid + 256 * t;
      int row = f >> 3, seg = f & 7;
      *(uint4*)&As[row * LDA + seg * 8] =
          *(const uint4*)&A[(m0 + row) * 512 + ak0 + seg * 8];
    }
#pragma unroll
    for (int t = 0; t < 2; ++t) {
      int f = tid + 256 * t;
      int row = f >> 3, seg = f & 7;
      *(uint4*)&Bs[row * LDA + seg * 8] =
          *(const uint4*)&B[(n0 + row) * 768 + k0 + seg * 8];
    }
    __syncthreads();
#pragma unroll
    for (int kk = 0; kk < TBK; kk += 32) {
      f16x8 bfr0 = *(const f16x8*)&Bs[(wn + l15) * LDA + kk + quad * 8];
      f16x8 bfr1 = *(const f16x8*)&Bs[(wn + 16 + l15) * LDA + kk + quad * 8];
#pragma unroll
      for (int mt = 0; mt < 4; ++mt) {
        f16x8 afr =
            *(const f16x8*)&As[(wm + mt * 16 + l15) * LDA + kk + quad * 8];
        acc[mt][0] = __builtin_amdgcn_mfma_f32_16x16x32_f16(afr, bfr0,
                                                            acc[mt][0], 0, 0,
                                                            0);
        acc[mt][1] = __builtin_amdgcn_mfma_f32_16x16x32_f16(afr, bfr1,
                                                            acc[mt][1], 0, 0,
                                                            0);
      }
    }
  }
#pragma unroll
  for (int mt = 0; mt < 4; ++mt) {
#pragma unroll
    for (int nt = 0; nt < 2; ++nt) {
      int col = n0 + wn + nt * 16 + l15;
      float bv = bias[col];
#pragma unroll
      for (int r = 0; r < 4; ++r) {
        int row = m0 + wm + mt * 16 + quad * 4 + r;
        epi(row, col, acc[mt][nt][r] + bv);
      }
    }
  }
}

// K2: qkv GEMM. q -> qcat split-fp16 [h][t][hi32|lo32]; k,v -> fp32 bufs
__global__ __launch_bounds__(256) void k_qkv_gemm(
    const _Float16* __restrict__ A, const _Float16* __restrict__ B,
    const float* __restrict__ bias, _Float16* __restrict__ qcat,
    float* __restrict__ kbuf, float* __restrict__ vbuf) {
  gemm_main(A, B, bias, [=](int row, int col, float val) {
    int c = col % 3;
    int rr = col / 3;
    int e = rr & 31;
    int h = rr >> 5;
    if (c == 0) {
      _Float16 hi, lo;
      f2h_split(val, hi, lo);
      qcat[(h * NM + row) * 64 + e] = hi;
      qcat[(h * NM + row) * 64 + 32 + e] = lo;
    } else {
      float* dst = (c == 1) ? kbuf : vbuf;
      dst[(h * NM + row) * HE + e] = val;
    }
  });
}

// K5: proj GEMM, dense output
__global__ __launch_bounds__(256) void k_proj(
    const _Float16* __restrict__ A, const _Float16* __restrict__ B,
    const float* __restrict__ bias, float* __restrict__ out) {
  gemm_main(A, B, bias,
            [=](int row, int col, float val) { out[row * DIM + col] = val; });
}

// K2b: kmc[h][ball][hi32|lo32] = split-fp16 of mean over m of kbuf
__global__ __launch_bounds__(256) void k_kmean(
    const float* __restrict__ kbuf, _Float16* __restrict__ kmc) {
  int tid = threadIdx.x;
  int gb = blockIdx.x * 8 + (tid >> 5);  // h*512 + ball
  int e = tid & 31;
  int h = gb >> 9, ball = gb & 511;
  float s = 0.f;
#pragma unroll
  for (int m = 0; m < BALL; ++m)
    s += kbuf[(h * NM + ball * BALL + m) * HE + e];
  float mean = s * (1.f / BALL);
  _Float16 hi, lo;
  f2h_split(mean, hi, lo);
  kmc[gb * 64 + e] = hi;
  kmc[gb * 64 + 32 + e] = lo;
}

// ---------------------------------------------------------------------------
// K3 v5: sim+top2 on MFMA. Block = 4 waves x 16 queries = 64 queries.
// kmean (split-fp16) staged in LDS in 4 chunks of 128 balls (stride 72,
// 2-way bank alias = free). Per 16x16 tile: 3 MFMAs (hiHI + loHI + hiLO),
// per-lane running top-2 (lane owns col=ball l15, rows quad*4+r), one
// cross-lane butterfly at the end -> topk int2.
// ---------------------------------------------------------------------------
#define LDK 72

__global__ __launch_bounds__(256) void k_sim_topk(
    const _Float16* __restrict__ qcat, const _Float16* __restrict__ kmc,
    int2* __restrict__ topk2) {
  __shared__ _Float16 km_s[128 * LDK];
  int tid = threadIdx.x;
  int h = blockIdx.y;
  int wv = tid >> 6, lane = tid & 63;
  int l15 = lane & 15, quad = lane >> 4;
  int q0w = blockIdx.x * 64 + wv * 16;

  // per-lane q fragments (row = query l15, k = quad*8..+7), loaded once
  const _Float16* qrow = &qcat[(h * NM + q0w + l15) * 64];
  f16x8 qhi = *(const f16x8*)&qrow[quad * 8];
  f16x8 qlo = *(const f16x8*)&qrow[32 + quad * 8];

  float v0[4], v1[4];
  int i0[4], i1[4];
#pragma unroll
  for (int r = 0; r < 4; ++r) {
    v0[r] = -1e30f; v1[r] = -1e30f; i0[r] = 0; i1[r] = 0;
  }

  for (int ch = 0; ch < 4; ++ch) {
    if (ch) __syncthreads();
    // stage 128 balls x 64 fp16 (hi|lo) into LDS
#pragma unroll
    for (int t = 0; t < 4; ++t) {
      int f = tid + 256 * t;           // 0..1023
      int row = f >> 3, seg = f & 7;   // 8 segs x 8 fp16
      *(uint4*)&km_s[row * LDK + seg * 8] =
          *(const uint4*)&kmc[(h * NBALLS + ch * 128 + row) * 64 + seg * 8];
    }
    __syncthreads();

#pragma unroll
    for (int tile = 0; tile < 8; ++tile) {
      const _Float16* bb = &km_s[(tile * 16 + l15) * LDK];
      f16x8 bhi = *(const f16x8*)&bb[quad * 8];
      f16x8 blo = *(const f16x8*)&bb[32 + quad * 8];
      f32x4 acc = {};
      acc = __builtin_amdgcn_mfma_f32_16x16x32_f16(qhi, bhi, acc, 0, 0, 0);
      acc = __builtin_amdgcn_mfma_f32_16x16x32_f16(qlo, bhi, acc, 0, 0, 0);
      acc = __builtin_amdgcn_mfma_f32_16x16x32_f16(qhi, blo, acc, 0, 0, 0);
      int ball = ch * 128 + tile * 16 + l15;
#pragma unroll
      for (int r = 0; r < 4; ++r) {
        float wv0 = acc[r];
        if (wv0 > v0[r]) {
          v1[r] = v0[r]; i1[r] = i0[r];
          v0[r] = wv0; i0[r] = ball;
        } else if (wv0 > v1[r]) {
          v1[r] = wv0; i1[r] = ball;
        }
      }
    }
  }

  // butterfly merge across the 16 lanes of each quad-group
#pragma unroll
  for (int m = 1; m < 16; m <<= 1) {
#pragma unroll
    for (int r = 0; r < 4; ++r) {
      float w0 = __shfl_xor(v0[r], m), w1 = __shfl_xor(v1[r], m);
      int j0 = __shfl_xor(i0[r], m), j1 = __shfl_xor(i1[r], m);
      merge_top2(v0[r], i0[r], v1[r], i1[r], w0, j0, w1, j1);
    }
  }
  if (l15 == 0) {
#pragma unroll
    for (int r = 0; r < 4; ++r) {
      int q = q0w + quad * 4 + r;
      topk2[h * NM + q] = make_int2(i0[r], i1[r]);
    }
  }
}

// ---------------------------------------------------------------------------
// K4: gather 2 balls' K/V, softmax, weighted-V. 4 (h,q) pairs per 256-thread
// block, one wave each. Output as hi/lo fp16 into acat (for proj GEMM).
// ---------------------------------------------------------------------------
__global__ __launch_bounds__(256) void k_attn(
    const _Float16* __restrict__ qcat, const float* __restrict__ kbuf,
    const float* __restrict__ vbuf, const int2* __restrict__ topk2,
    _Float16* __restrict__ acat) {
  __shared__ float q_s[4][HE];
  __shared__ float ks[4][32 * 33];
  __shared__ float vs[4][32 * 33];
  __shared__ float attw[4][32];
  int wv = threadIdx.x >> 6;
  int tid = threadIdx.x & 63;
  int idx = blockIdx.x * 4 + wv;
  int h = idx >> 13, t = idx & (NM - 1);

  int2 tk = topk2[h * NM + t];
  int b0 = tk.x, b1 = tk.y;

  if (tid < HE) {
    const _Float16* qr = &qcat[(h * NM + t) * 64];
    q_s[wv][tid] = (float)qr[tid] + (float)qr[32 + tid];
  }
#pragma unroll
  for (int i = 0; i < 16; ++i) {
    int pidx = tid + 64 * i;  // 0..1023
    int j = pidx >> 5, e = pidx & 31;
    int ball = (j < 16) ? b0 : b1;
    int m = j & 15;
    int src = (h * NM + ball * BALL + m) * HE + e;
    ks[wv][j * 33 + e] = kbuf[src];
    vs[wv][j * 33 + e] = vbuf[src];
  }
  __syncthreads();
  int j = tid & 31, half = tid >> 5;
  int e0 = half * 16;
  float partial = 0.f;
#pragma unroll
  for (int e = 0; e < 16; ++e)
    partial += q_s[wv][e0 + e] * ks[wv][j * 33 + e0 + e];
  partial += __shfl_xor(partial, 32);
  float logit = partial * 0.17677669529663687f;  // 1/sqrt(32)
  float mx = logit;
#pragma unroll
  for (int mk = 1; mk <= 16; mk <<= 1) mx = fmaxf(mx, __shfl_xor(mx, mk));
  float pexp = __expf(logit - mx);
  float sum = pexp;
#pragma unroll
  for (int mk = 1; mk <= 16; mk <<= 1) sum += __shfl_xor(sum, mk);
  float attn = pexp / sum;
  if (tid < 32) attw[wv][j] = attn;
  __syncthreads();
  int e = tid & 31, j0 = half * 16;
  float po = 0.f;
#pragma unroll
  for (int jj = 0; jj < 16; ++jj)
    po += attw[wv][j0 + jj] * vs[wv][(j0 + jj) * 33 + e];
  po += __shfl_xor(po, 32);
  if (tid < 32) {
    _Float16 hi, lo;
    f2h_split(po, hi, lo);
    acat[t * 512 + h * HE + e] = hi;
    acat[t * 512 + 256 + h * HE + e] = lo;
  }
}

extern "C" void kernel_launch(void* const* d_in, const int* in_sizes, int n_in,
                              void* d_out, int out_size, void* d_ws,
                              size_t ws_size, hipStream_t stream) {
  const float* x = (const float*)d_in[0];
  const float* pos = (const float*)d_in[1];
  const float* Wqkv = (const float*)d_in[2];
  const float* bqkv = (const float*)d_in[3];
  const float* Wpe = (const float*)d_in[4];
  const float* bpe = (const float*)d_in[5];
  const float* Wproj = (const float*)d_in[6];
  const float* bproj = (const float*)d_in[7];
  float* out = (float*)d_out;

  float* kbuf = (float*)d_ws;                    // 8 MB
  float* vbuf = kbuf + NH * NM * HE;             // 8 MB
  _Float16* qcat = (_Float16*)(vbuf + NH * NM * HE);  // 8 MB
  _Float16* kmc = qcat + NH * NM * 64;           // 512 KB
  int2* topk2 = (int2*)(kmc + NH * NBALLS * 64); // 512 KB
  _Float16* xcat = (_Float16*)(topk2 + NH * NM); // 8 MB
  _Float16* acat = xcat;  // alias: xcat dead after k_qkv_gemm
  _Float16* Bq = xcat + NM * 512;                // 1.2 MB
  _Float16* Bp = Bq + 768 * 768;                 // 0.4 MB

  k_posembed<<<NBALLS, 256, 0, stream>>>(x, pos, Wpe, bpe, xcat);
  k_wsplit<<<1024, 256, 0, stream>>>(Wqkv, Wproj, Bq, Bp);
  k_qkv_gemm<<<dim3(NM / 128, 768 / 64), 256, 0, stream>>>(xcat, Bq, bqkv,
                                                           qcat, kbuf, vbuf);
  k_kmean<<<(NH * NBALLS) / 8, 256, 0, stream>>>(kbuf, kmc);
  k_sim_topk<<<dim3(NM / 64, NH), 256, 0, stream>>>(qcat, kmc, topk2);
  k_attn<<<NH * NM / 4, 256, 0, stream>>>(qcat, kbuf, vbuf, topk2, acat);
  k_proj<<<dim3(NM / 128, DIM / 64), 256, 0, stream>>>(acat, Bp, bproj, out);
}

// Round 9
// 182.187 us; speedup vs baseline: 1.7997x; 1.0881x over previous
//
#include <hip/hip_runtime.h>

#define DIM 256
#define NH 8
#define HE 32          // head dim E
#define BALL 16        // ball size M
#define NBALLS 512
#define NM 8192

typedef _Float16 f16x8 __attribute__((ext_vector_type(8)));
typedef float f32x4 __attribute__((ext_vector_type(4)));

// fp16 2-term split: x = hi + lo, residual ~2^-24 |x| (fp32-quality)
__device__ __forceinline__ void f2h_split(float val, _Float16& hi,
                                          _Float16& lo) {
  hi = (_Float16)val;
  lo = (_Float16)(val - (float)hi);
}

__device__ __forceinline__ void merge_top2(float& v0, int& i0, float& v1,
                                           int& i1, float w0, int j0,
                                           float w1, int j1) {
  if (w0 > v0) {
    float tv; int ti;
    tv = v0; v0 = w0; w0 = tv; ti = i0; i0 = j0; j0 = ti;
    tv = v1; v1 = w1; w1 = tv; ti = i1; i1 = j1; j1 = ti;
  }
  if (w0 > v1) { v1 = w0; i1 = j0; }
}

// ---------------------------------------------------------------------------
// K1: x' = x + rel @ W_pe^T + b_pe; emit hi/lo fp16 into xcat[t][0:256|256:512]
// ---------------------------------------------------------------------------
__global__ __launch_bounds__(256) void k_posembed(
    const float* __restrict__ x, const float* __restrict__ pos,
    const float* __restrict__ Wpe, const float* __restrict__ bpe,
    _Float16* __restrict__ xcat) {
  __shared__ float ps[BALL * 3];
  __shared__ float mean_s[3];
  int ball = blockIdx.x;
  int tid = threadIdx.x;
  if (tid < BALL * 3) ps[tid] = pos[ball * BALL * 3 + tid];
  __syncthreads();
  if (tid < 3) {
    float s = 0.f;
    for (int m = 0; m < BALL; ++m) s += ps[m * 3 + tid];
    mean_s[tid] = s * (1.f / BALL);
  }
  __syncthreads();
  int d = tid;
  float w0 = Wpe[d * 3 + 0], w1 = Wpe[d * 3 + 1], w2 = Wpe[d * 3 + 2];
  float bp = bpe[d];
  float m0 = mean_s[0], m1 = mean_s[1], m2 = mean_s[2];
  for (int m = 0; m < BALL; ++m) {
    int t = ball * BALL + m;
    float r0 = ps[m * 3 + 0] - m0;
    float r1 = ps[m * 3 + 1] - m1;
    float r2 = ps[m * 3 + 2] - m2;
    float val = x[t * DIM + d] + r0 * w0 + r1 * w1 + r2 * w2 + bp;
    _Float16 hi, lo;
    f2h_split(val, hi, lo);
    xcat[t * 512 + d] = hi;
    xcat[t * 512 + 256 + d] = lo;
  }
}

// ---------------------------------------------------------------------------
// K1b: split weights into concatenated-K fp16 form.
// B layout [N][768]: cols 0:256 = hi, 256:512 = hi (dup), 512:768 = lo
// ---------------------------------------------------------------------------
__global__ __launch_bounds__(256) void k_wsplit(
    const float* __restrict__ Wq, const float* __restrict__ Wp,
    _Float16* __restrict__ Bq, _Float16* __restrict__ Bp) {
  int n = blockIdx.x, k = threadIdx.x;
  if (n < 768) {
    _Float16 hi, lo;
    f2h_split(Wq[n * 256 + k], hi, lo);
    Bq[n * 768 + k] = hi;
    Bq[n * 768 + 256 + k] = hi;
    Bq[n * 768 + 512 + k] = lo;
  } else {
    int r = n - 768;
    _Float16 hi, lo;
    f2h_split(Wp[r * 256 + k], hi, lo);
    Bp[r * 768 + k] = hi;
    Bp[r * 768 + 256 + k] = hi;
    Bp[r * 768 + 512 + k] = lo;
  }
}

// ---------------------------------------------------------------------------
// Split-fp16 MFMA GEMM (verified layout). Epilogue: functor(row, col, val).
// ---------------------------------------------------------------------------
#define TBK 64
#define LDA 72

template <typename Epi>
__device__ __forceinline__ void gemm_main(const _Float16* __restrict__ A,
                                          const _Float16* __restrict__ B,
                                          const float* __restrict__ bias,
                                          Epi epi) {
  __shared__ _Float16 As[128 * LDA];
  __shared__ _Float16 Bs[64 * LDA];
  int tid = threadIdx.x;
  int m0 = blockIdx.x * 128;
  int n0 = blockIdx.y * 64;
  int w = tid >> 6, lane = tid & 63;
  int wm = (w >> 1) * 64, wn = (w & 1) * 32;
  int l15 = lane & 15, quad = lane >> 4;
  f32x4 acc[4][2] = {};
  for (int k0 = 0; k0 < 768; k0 += TBK) {
    int ak0 = (k0 < 512) ? k0 : (k0 - 512);
    if (k0) __syncthreads();
#pragma unroll
    for (int t = 0; t < 4; ++t) {
      int f = tid + 256 * t;
      int row = f >> 3, seg = f & 7;
      *(uint4*)&As[row * LDA + seg * 8] =
          *(const uint4*)&A[(m0 + row) * 512 + ak0 + seg * 8];
    }
#pragma unroll
    for (int t = 0; t < 2; ++t) {
      int f = tid + 256 * t;
      int row = f >> 3, seg = f & 7;
      *(uint4*)&Bs[row * LDA + seg * 8] =
          *(const uint4*)&B[(n0 + row) * 768 + k0 + seg * 8];
    }
    __syncthreads();
#pragma unroll
    for (int kk = 0; kk < TBK; kk += 32) {
      f16x8 bfr0 = *(const f16x8*)&Bs[(wn + l15) * LDA + kk + quad * 8];
      f16x8 bfr1 = *(const f16x8*)&Bs[(wn + 16 + l15) * LDA + kk + quad * 8];
#pragma unroll
      for (int mt = 0; mt < 4; ++mt) {
        f16x8 afr =
            *(const f16x8*)&As[(wm + mt * 16 + l15) * LDA + kk + quad * 8];
        acc[mt][0] = __builtin_amdgcn_mfma_f32_16x16x32_f16(afr, bfr0,
                                                            acc[mt][0], 0, 0,
                                                            0);
        acc[mt][1] = __builtin_amdgcn_mfma_f32_16x16x32_f16(afr, bfr1,
                                                            acc[mt][1], 0, 0,
                                                            0);
      }
    }
  }
#pragma unroll
  for (int mt = 0; mt < 4; ++mt) {
#pragma unroll
    for (int nt = 0; nt < 2; ++nt) {
      int col = n0 + wn + nt * 16 + l15;
      float bv = bias[col];
#pragma unroll
      for (int r = 0; r < 4; ++r) {
        int row = m0 + wm + mt * 16 + quad * 4 + r;
        epi(row, col, acc[mt][nt][r] + bv);
      }
    }
  }
}

// K2: qkv GEMM. q -> qcat split-fp16; k -> kbuf fp32 (kmean) + kv16 fp16;
// v -> kv16 fp16 only.
__global__ __launch_bounds__(256) void k_qkv_gemm(
    const _Float16* __restrict__ A, const _Float16* __restrict__ B,
    const float* __restrict__ bias, _Float16* __restrict__ qcat,
    float* __restrict__ kbuf, _Float16* __restrict__ kv16) {
  gemm_main(A, B, bias, [=](int row, int col, float val) {
    int c = col % 3;
    int rr = col / 3;
    int e = rr & 31;
    int h = rr >> 5;
    if (c == 0) {
      _Float16 hi, lo;
      f2h_split(val, hi, lo);
      qcat[(h * NM + row) * 64 + e] = hi;
      qcat[(h * NM + row) * 64 + 32 + e] = lo;
    } else if (c == 1) {
      kbuf[(h * NM + row) * HE + e] = val;
      kv16[(h * NM + row) * 64 + e] = (_Float16)val;
    } else {
      kv16[(h * NM + row) * 64 + 32 + e] = (_Float16)val;
    }
  });
}

// K5: proj GEMM, dense output
__global__ __launch_bounds__(256) void k_proj(
    const _Float16* __restrict__ A, const _Float16* __restrict__ B,
    const float* __restrict__ bias, float* __restrict__ out) {
  gemm_main(A, B, bias,
            [=](int row, int col, float val) { out[row * DIM + col] = val; });
}

// K2b: kmc[h][ball][hi32|lo32] = split-fp16 of mean over m of kbuf (fp32)
__global__ __launch_bounds__(256) void k_kmean(
    const float* __restrict__ kbuf, _Float16* __restrict__ kmc) {
  int tid = threadIdx.x;
  int gb = blockIdx.x * 8 + (tid >> 5);  // h*512 + ball
  int e = tid & 31;
  int h = gb >> 9, ball = gb & 511;
  float s = 0.f;
#pragma unroll
  for (int m = 0; m < BALL; ++m)
    s += kbuf[(h * NM + ball * BALL + m) * HE + e];
  float mean = s * (1.f / BALL);
  _Float16 hi, lo;
  f2h_split(mean, hi, lo);
  kmc[gb * 64 + e] = hi;
  kmc[gb * 64 + 32 + e] = lo;
}

// ---------------------------------------------------------------------------
// K3: sim+top2 on MFMA. Block = 4 waves x 16 queries = 64 queries.
// ---------------------------------------------------------------------------
#define LDK 72

__global__ __launch_bounds__(256) void k_sim_topk(
    const _Float16* __restrict__ qcat, const _Float16* __restrict__ kmc,
    int2* __restrict__ topk2) {
  __shared__ _Float16 km_s[128 * LDK];
  int tid = threadIdx.x;
  int h = blockIdx.y;
  int wv = tid >> 6, lane = tid & 63;
  int l15 = lane & 15, quad = lane >> 4;
  int q0w = blockIdx.x * 64 + wv * 16;

  const _Float16* qrow = &qcat[(h * NM + q0w + l15) * 64];
  f16x8 qhi = *(const f16x8*)&qrow[quad * 8];
  f16x8 qlo = *(const f16x8*)&qrow[32 + quad * 8];

  float v0[4], v1[4];
  int i0[4], i1[4];
#pragma unroll
  for (int r = 0; r < 4; ++r) {
    v0[r] = -1e30f; v1[r] = -1e30f; i0[r] = 0; i1[r] = 0;
  }

  for (int ch = 0; ch < 4; ++ch) {
    if (ch) __syncthreads();
#pragma unroll
    for (int t = 0; t < 4; ++t) {
      int f = tid + 256 * t;           // 0..1023
      int row = f >> 3, seg = f & 7;   // 8 segs x 8 fp16
      *(uint4*)&km_s[row * LDK + seg * 8] =
          *(const uint4*)&kmc[(h * NBALLS + ch * 128 + row) * 64 + seg * 8];
    }
    __syncthreads();

#pragma unroll
    for (int tile = 0; tile < 8; ++tile) {
      const _Float16* bb = &km_s[(tile * 16 + l15) * LDK];
      f16x8 bhi = *(const f16x8*)&bb[quad * 8];
      f16x8 blo = *(const f16x8*)&bb[32 + quad * 8];
      f32x4 acc = {};
      acc = __builtin_amdgcn_mfma_f32_16x16x32_f16(qhi, bhi, acc, 0, 0, 0);
      acc = __builtin_amdgcn_mfma_f32_16x16x32_f16(qlo, bhi, acc, 0, 0, 0);
      acc = __builtin_amdgcn_mfma_f32_16x16x32_f16(qhi, blo, acc, 0, 0, 0);
      int ball = ch * 128 + tile * 16 + l15;
#pragma unroll
      for (int r = 0; r < 4; ++r) {
        float wv0 = acc[r];
        if (wv0 > v0[r]) {
          v1[r] = v0[r]; i1[r] = i0[r];
          v0[r] = wv0; i0[r] = ball;
        } else if (wv0 > v1[r]) {
          v1[r] = wv0; i1[r] = ball;
        }
      }
    }
  }

#pragma unroll
  for (int m = 1; m < 16; m <<= 1) {
#pragma unroll
    for (int r = 0; r < 4; ++r) {
      float w0 = __shfl_xor(v0[r], m), w1 = __shfl_xor(v1[r], m);
      int j0 = __shfl_xor(i0[r], m), j1 = __shfl_xor(i1[r], m);
      merge_top2(v0[r], i0[r], v1[r], i1[r], w0, j0, w1, j1);
    }
  }
  if (l15 == 0) {
#pragma unroll
    for (int r = 0; r < 4; ++r) {
      int q = q0w + quad * 4 + r;
      topk2[h * NM + q] = make_int2(i0[r], i1[r]);
    }
  }
}

// ---------------------------------------------------------------------------
// K4 v2: fp16 interleaved K/V gather. 4 (h,q) waves per 256-thread block.
// Per wave: 4 global_load_dwordx4 stage 2 balls (4 KB) of kv16 into LDS
// (row stride 72 fp16: staging writes and K-reads both hit the 8-clk
// conflict-free minimum). Softmax, weighted-V, split-fp16 out to acat.
// ---------------------------------------------------------------------------
__global__ __launch_bounds__(256) void k_attn(
    const _Float16* __restrict__ qcat, const _Float16* __restrict__ kv16,
    const int2* __restrict__ topk2, _Float16* __restrict__ acat) {
  __shared__ _Float16 kv_s[4][32 * 72];
  __shared__ float q_s[4][HE];
  __shared__ float attw[4][32];
  int wv = threadIdx.x >> 6;
  int tid = threadIdx.x & 63;
  int idx = blockIdx.x * 4 + wv;
  int h = idx >> 13, t = idx & (NM - 1);

  int2 tk = topk2[h * NM + t];

  if (tid < HE) {
    const _Float16* qr = &qcat[(h * NM + t) * 64];
    q_s[wv][tid] = (float)qr[tid] + (float)qr[32 + tid];
  }
  // stage 2 balls x 16 tokens x (32 k + 32 v fp16) = 256 x 16B granules
#pragma unroll
  for (int i = 0; i < 4; ++i) {
    int g = tid + 64 * i;            // 0..255
    int j = g >> 3, seg = g & 7;     // token row j, 16B segment
    int ball = (j < 16) ? tk.x : tk.y;
    int m = j & 15;
    *(uint4*)&kv_s[wv][j * 72 + seg * 8] =
        *(const uint4*)&kv16[(h * NM + ball * BALL + m) * 64 + seg * 8];
  }
  __syncthreads();

  int j = tid & 31, half = tid >> 5;
  int e0 = half * 16;
  float partial = 0.f;
  {
    f16x8 ka = *(const f16x8*)&kv_s[wv][j * 72 + e0];
    f16x8 kb = *(const f16x8*)&kv_s[wv][j * 72 + e0 + 8];
#pragma unroll
    for (int e = 0; e < 8; ++e) {
      partial += q_s[wv][e0 + e] * (float)ka[e];
      partial += q_s[wv][e0 + 8 + e] * (float)kb[e];
    }
  }
  partial += __shfl_xor(partial, 32);
  float logit = partial * 0.17677669529663687f;  // 1/sqrt(32)
  float mx = logit;
#pragma unroll
  for (int mk = 1; mk <= 16; mk <<= 1) mx = fmaxf(mx, __shfl_xor(mx, mk));
  float pexp = __expf(logit - mx);
  float sum = pexp;
#pragma unroll
  for (int mk = 1; mk <= 16; mk <<= 1) sum += __shfl_xor(sum, mk);
  float attn = pexp / sum;
  if (tid < 32) attw[wv][j] = attn;
  __syncthreads();

  int e = tid & 31, j0 = half * 16;
  float po = 0.f;
#pragma unroll
  for (int jj = 0; jj < 16; ++jj)
    po += attw[wv][j0 + jj] * (float)kv_s[wv][(j0 + jj) * 72 + 32 + e];
  po += __shfl_xor(po, 32);
  if (tid < 32) {
    _Float16 hi, lo;
    f2h_split(po, hi, lo);
    acat[t * 512 + h * HE + e] = hi;
    acat[t * 512 + 256 + h * HE + e] = lo;
  }
}

extern "C" void kernel_launch(void* const* d_in, const int* in_sizes, int n_in,
                              void* d_out, int out_size, void* d_ws,
                              size_t ws_size, hipStream_t stream) {
  const float* x = (const float*)d_in[0];
  const float* pos = (const float*)d_in[1];
  const float* Wqkv = (const float*)d_in[2];
  const float* bqkv = (const float*)d_in[3];
  const float* Wpe = (const float*)d_in[4];
  const float* bpe = (const float*)d_in[5];
  const float* Wproj = (const float*)d_in[6];
  const float* bproj = (const float*)d_in[7];
  float* out = (float*)d_out;

  float* kbuf = (float*)d_ws;                         // 8 MB (kmean only)
  _Float16* kv16 = (_Float16*)(kbuf + NH * NM * HE);  // 8 MB
  _Float16* qcat = kv16 + NH * NM * 64;               // 8 MB
  _Float16* kmc = qcat + NH * NM * 64;                // 512 KB
  int2* topk2 = (int2*)(kmc + NH * NBALLS * 64);      // 512 KB
  _Float16* xcat = (_Float16*)(topk2 + NH * NM);      // 8 MB
  _Float16* acat = xcat;  // alias: xcat dead after k_qkv_gemm
  _Float16* Bq = xcat + NM * 512;                     // 1.2 MB
  _Float16* Bp = Bq + 768 * 768;                      // 0.4 MB

  k_posembed<<<NBALLS, 256, 0, stream>>>(x, pos, Wpe, bpe, xcat);
  k_wsplit<<<1024, 256, 0, stream>>>(Wqkv, Wproj, Bq, Bp);
  k_qkv_gemm<<<dim3(NM / 128, 768 / 64), 256, 0, stream>>>(xcat, Bq, bqkv,
                                                           qcat, kbuf, kv16);
  k_kmean<<<(NH * NBALLS) / 8, 256, 0, stream>>>(kbuf, kmc);
  k_sim_topk<<<dim3(NM / 64, NH), 256, 0, stream>>>(qcat, kmc, topk2);
  k_attn<<<NH * NM / 4, 256, 0, stream>>>(qcat, kv16, topk2, acat);
  k_proj<<<dim3(NM / 128, DIM / 64), 256, 0, stream>>>(acat, Bp, bproj, out);
}

// Round 10
// 160.318 us; speedup vs baseline: 2.0452x; 1.1364x over previous
//
#include <hip/hip_runtime.h>

#define DIM 256
#define NH 8
#define HE 32          // head dim E
#define BALL 16        // ball size M
#define NBALLS 512
#define NM 8192

typedef _Float16 f16x8 __attribute__((ext_vector_type(8)));
typedef float f32x4 __attribute__((ext_vector_type(4)));

// fp16 2-term split: x = hi + lo, residual ~2^-24 |x| (fp32-quality)
__device__ __forceinline__ void f2h_split(float val, _Float16& hi,
                                          _Float16& lo) {
  hi = (_Float16)val;
  lo = (_Float16)(val - (float)hi);
}

__device__ __forceinline__ void merge_top2(float& v0, int& i0, float& v1,
                                           int& i1, float w0, int j0,
                                           float w1, int j1) {
  if (w0 > v0) {
    float tv; int ti;
    tv = v0; v0 = w0; w0 = tv; ti = i0; i0 = j0; j0 = ti;
    tv = v1; v1 = w1; w1 = tv; ti = i1; i1 = j1; j1 = ti;
  }
  if (w0 > v1) { v1 = w0; i1 = j0; }
}

// async global->LDS, 16B per lane; LDS dest = wave-uniform base + lane*16
__device__ __forceinline__ void gld_lds16(_Float16* lds, const _Float16* g) {
  __builtin_amdgcn_global_load_lds(
      (const __attribute__((address_space(1))) unsigned int*)g,
      (__attribute__((address_space(3))) unsigned int*)lds, 16, 0, 0);
}

// ---------------------------------------------------------------------------
// K1 (fused): blocks [0,512): posembed -> xcat[t][hi256|lo256]
//             blocks [512,1536): weight split -> Bq/Bp concatenated-K fp16
//             (B layout [N][768]: 0:256=hi, 256:512=hi dup, 512:768=lo)
// ---------------------------------------------------------------------------
__global__ __launch_bounds__(256) void k_prep(
    const float* __restrict__ x, const float* __restrict__ pos,
    const float* __restrict__ Wpe, const float* __restrict__ bpe,
    _Float16* __restrict__ xcat, const float* __restrict__ Wq,
    const float* __restrict__ Wp, _Float16* __restrict__ Bq,
    _Float16* __restrict__ Bp) {
  if (blockIdx.x >= NBALLS) {
    int n = blockIdx.x - NBALLS;  // 0..1023
    int k = threadIdx.x;
    if (n < 768) {
      _Float16 hi, lo;
      f2h_split(Wq[n * 256 + k], hi, lo);
      Bq[n * 768 + k] = hi;
      Bq[n * 768 + 256 + k] = hi;
      Bq[n * 768 + 512 + k] = lo;
    } else {
      int r = n - 768;
      _Float16 hi, lo;
      f2h_split(Wp[r * 256 + k], hi, lo);
      Bp[r * 768 + k] = hi;
      Bp[r * 768 + 256 + k] = hi;
      Bp[r * 768 + 512 + k] = lo;
    }
    return;
  }
  __shared__ float ps[BALL * 3];
  __shared__ float mean_s[3];
  int ball = blockIdx.x;
  int tid = threadIdx.x;
  if (tid < BALL * 3) ps[tid] = pos[ball * BALL * 3 + tid];
  __syncthreads();
  if (tid < 3) {
    float s = 0.f;
    for (int m = 0; m < BALL; ++m) s += ps[m * 3 + tid];
    mean_s[tid] = s * (1.f / BALL);
  }
  __syncthreads();
  int d = tid;
  float w0 = Wpe[d * 3 + 0], w1 = Wpe[d * 3 + 1], w2 = Wpe[d * 3 + 2];
  float bp = bpe[d];
  float m0 = mean_s[0], m1 = mean_s[1], m2 = mean_s[2];
  for (int m = 0; m < BALL; ++m) {
    int t = ball * BALL + m;
    float r0 = ps[m * 3 + 0] - m0;
    float r1 = ps[m * 3 + 1] - m1;
    float r2 = ps[m * 3 + 2] - m2;
    float val = x[t * DIM + d] + r0 * w0 + r1 * w1 + r2 * w2 + bp;
    _Float16 hi, lo;
    f2h_split(val, hi, lo);
    xcat[t * 512 + d] = hi;
    xcat[t * 512 + 256 + d] = lo;
  }
}

// ---------------------------------------------------------------------------
// Split-fp16 MFMA GEMM core with async LDS staging + XOR-swizzled layout.
// LDS(row, s) holds global granule (row, s ^ (row&7)); read of logical
// (row, ls) uses physical ls^(row&7) -> round-trips to logical ls.
// Tile 128x64, BK=64, wave-tile 64x32 = 4x2 mfma_f32_16x16x32_f16.
// ---------------------------------------------------------------------------
#define TBK 64

template <typename AF, typename BF, typename Epi>
__device__ __forceinline__ void gemm_core(AF a_addr, BF b_addr,
                                          const float* __restrict__ bias,
                                          int m0, int n0, Epi epi) {
  __shared__ _Float16 As[128 * 64];
  __shared__ _Float16 Bs[64 * 64];
  int tid = threadIdx.x;
  int w = tid >> 6, lane = tid & 63;
  int wm = (w >> 1) * 64, wn = (w & 1) * 32;
  int l15 = lane & 15, quad = lane >> 4;
  int sw = l15 & 7;  // swizzle key for all fragment rows (row&7 == l15&7)
  f32x4 acc[4][2] = {};
  for (int k0 = 0; k0 < 768; k0 += TBK) {
    int ak0 = (k0 < 512) ? k0 : (k0 - 512);
    if (k0) __syncthreads();
#pragma unroll
    for (int t = 0; t < 4; ++t) {
      int f = tid + 256 * t;  // 0..1023
      int row = f >> 3, sg = (f & 7) ^ (row & 7);
      gld_lds16(&As[f * 8], a_addr(m0 + row, ak0 + sg * 8));
    }
#pragma unroll
    for (int t = 0; t < 2; ++t) {
      int f = tid + 256 * t;  // 0..511
      int row = f >> 3, sg = (f & 7) ^ (row & 7);
      gld_lds16(&Bs[f * 8], b_addr(n0 + row, k0 + sg * 8));
    }
    __syncthreads();
#pragma unroll
    for (int kk = 0; kk < TBK; kk += 32) {
      int ls = (kk >> 3) + quad;          // logical 16B segment
      int psg = (ls ^ sw) * 8;            // physical element offset
      f16x8 bfr0 = *(const f16x8*)&Bs[(wn + l15) * 64 + psg];
      f16x8 bfr1 = *(const f16x8*)&Bs[(wn + 16 + l15) * 64 + psg];
#pragma unroll
      for (int mt = 0; mt < 4; ++mt) {
        f16x8 afr = *(const f16x8*)&As[(wm + mt * 16 + l15) * 64 + psg];
        acc[mt][0] = __builtin_amdgcn_mfma_f32_16x16x32_f16(afr, bfr0,
                                                            acc[mt][0], 0, 0,
                                                            0);
        acc[mt][1] = __builtin_amdgcn_mfma_f32_16x16x32_f16(afr, bfr1,
                                                            acc[mt][1], 0, 0,
                                                            0);
      }
    }
  }
#pragma unroll
  for (int mt = 0; mt < 4; ++mt) {
#pragma unroll
    for (int nt = 0; nt < 2; ++nt) {
      int col = n0 + wn + nt * 16 + l15;
      float bv = bias[col];
#pragma unroll
      for (int r = 0; r < 4; ++r) {
        int row = m0 + wm + mt * 16 + quad * 4 + r;
        epi(row, col, acc[mt][nt][r] + bv);
      }
    }
  }
}

// K2: qkv GEMM. q -> qcat split-fp16; k -> kbuf fp32 (kmean) + kv16 fp16;
// v -> kv16 fp16 only.
__global__ __launch_bounds__(256) void k_qkv_gemm(
    const _Float16* __restrict__ A, const _Float16* __restrict__ B,
    const float* __restrict__ bias, _Float16* __restrict__ qcat,
    float* __restrict__ kbuf, _Float16* __restrict__ kv16) {
  int m0 = blockIdx.x * 128, n0 = blockIdx.y * 64;
  gemm_core(
      [=](int r, int k) { return &A[r * 512 + k]; },
      [=](int r, int k) { return &B[r * 768 + k]; }, bias, m0, n0,
      [=](int row, int col, float val) {
        int c = col % 3;
        int rr = col / 3;
        int e = rr & 31;
        int h = rr >> 5;
        if (c == 0) {
          _Float16 hi, lo;
          f2h_split(val, hi, lo);
          qcat[(h * NM + row) * 64 + e] = hi;
          qcat[(h * NM + row) * 64 + 32 + e] = lo;
        } else if (c == 1) {
          kbuf[(h * NM + row) * HE + e] = val;
          kv16[(h * NM + row) * 64 + e] = (_Float16)val;
        } else {
          kv16[(h * NM + row) * 64 + 32 + e] = (_Float16)val;
        }
      });
}

// K5: proj GEMM. A = acat in [half][h][t][32] layout (coalesced attn writes)
__global__ __launch_bounds__(256) void k_proj(
    const _Float16* __restrict__ acat, const _Float16* __restrict__ B,
    const float* __restrict__ bias, float* __restrict__ out) {
  int m0 = blockIdx.x * 128, n0 = blockIdx.y * 64;
  gemm_core(
      [=](int r, int k) {
        int half = k >> 8, hh = (k >> 5) & 7, e0 = k & 31;
        return &acat[((half * NH + hh) * NM + r) * 32 + e0];
      },
      [=](int r, int k) { return &B[r * 768 + k]; }, bias, m0, n0,
      [=](int row, int col, float val) { out[row * DIM + col] = val; });
}

// K2b: kmc[h][ball][hi32|lo32] = split-fp16 of mean over m of kbuf (fp32)
__global__ __launch_bounds__(256) void k_kmean(
    const float* __restrict__ kbuf, _Float16* __restrict__ kmc) {
  int tid = threadIdx.x;
  int gb = blockIdx.x * 8 + (tid >> 5);  // h*512 + ball
  int e = tid & 31;
  int h = gb >> 9, ball = gb & 511;
  float s = 0.f;
#pragma unroll
  for (int m = 0; m < BALL; ++m)
    s += kbuf[(h * NM + ball * BALL + m) * HE + e];
  float mean = s * (1.f / BALL);
  _Float16 hi, lo;
  f2h_split(mean, hi, lo);
  kmc[gb * 64 + e] = hi;
  kmc[gb * 64 + 32 + e] = lo;
}

// ---------------------------------------------------------------------------
// K3: sim+top2 on MFMA. Block = 4 waves, 128 queries (2 q-tiles per wave).
// kmean staged via global_load_lds with the same XOR swizzle.
// ---------------------------------------------------------------------------
__global__ __launch_bounds__(256) void k_sim_topk(
    const _Float16* __restrict__ qcat, const _Float16* __restrict__ kmc,
    int2* __restrict__ topk2) {
  __shared__ _Float16 km_s[128 * 64];
  int tid = threadIdx.x;
  int h = blockIdx.y;
  int wv = tid >> 6, lane = tid & 63;
  int l15 = lane & 15, quad = lane >> 4;
  int sw = l15 & 7;
  int q0 = blockIdx.x * 128 + wv * 16;
  int q1 = q0 + 64;

  const _Float16* qr0 = &qcat[(h * NM + q0 + l15) * 64];
  const _Float16* qr1 = &qcat[(h * NM + q1 + l15) * 64];
  f16x8 qhi0 = *(const f16x8*)&qr0[quad * 8];
  f16x8 qlo0 = *(const f16x8*)&qr0[32 + quad * 8];
  f16x8 qhi1 = *(const f16x8*)&qr1[quad * 8];
  f16x8 qlo1 = *(const f16x8*)&qr1[32 + quad * 8];

  float v0[2][4], v1[2][4];
  int i0[2][4], i1[2][4];
#pragma unroll
  for (int g = 0; g < 2; ++g)
#pragma unroll
    for (int r = 0; r < 4; ++r) {
      v0[g][r] = -1e30f; v1[g][r] = -1e30f; i0[g][r] = 0; i1[g][r] = 0;
    }

  for (int ch = 0; ch < 4; ++ch) {
    if (ch) __syncthreads();
#pragma unroll
    for (int t = 0; t < 4; ++t) {
      int f = tid + 256 * t;  // 0..1023
      int row = f >> 3, sg = (f & 7) ^ (row & 7);
      gld_lds16(&km_s[f * 8],
                &kmc[(h * NBALLS + ch * 128 + row) * 64 + sg * 8]);
    }
    __syncthreads();

#pragma unroll
    for (int tile = 0; tile < 8; ++tile) {
      const _Float16* bb = &km_s[(tile * 16 + l15) * 64];
      f16x8 bhi = *(const f16x8*)&bb[(quad ^ sw) * 8];
      f16x8 blo = *(const f16x8*)&bb[((4 + quad) ^ sw) * 8];
      int ball = ch * 128 + tile * 16 + l15;
      f32x4 a0 = {};
      a0 = __builtin_amdgcn_mfma_f32_16x16x32_f16(qhi0, bhi, a0, 0, 0, 0);
      a0 = __builtin_amdgcn_mfma_f32_16x16x32_f16(qlo0, bhi, a0, 0, 0, 0);
      a0 = __builtin_amdgcn_mfma_f32_16x16x32_f16(qhi0, blo, a0, 0, 0, 0);
      f32x4 a1 = {};
      a1 = __builtin_amdgcn_mfma_f32_16x16x32_f16(qhi1, bhi, a1, 0, 0, 0);
      a1 = __builtin_amdgcn_mfma_f32_16x16x32_f16(qlo1, bhi, a1, 0, 0, 0);
      a1 = __builtin_amdgcn_mfma_f32_16x16x32_f16(qhi1, blo, a1, 0, 0, 0);
#pragma unroll
      for (int r = 0; r < 4; ++r) {
        float s0 = a0[r];
        if (s0 > v0[0][r]) {
          v1[0][r] = v0[0][r]; i1[0][r] = i0[0][r];
          v0[0][r] = s0; i0[0][r] = ball;
        } else if (s0 > v1[0][r]) {
          v1[0][r] = s0; i1[0][r] = ball;
        }
        float s1 = a1[r];
        if (s1 > v0[1][r]) {
          v1[1][r] = v0[1][r]; i1[1][r] = i0[1][r];
          v0[1][r] = s1; i0[1][r] = ball;
        } else if (s1 > v1[1][r]) {
          v1[1][r] = s1; i1[1][r] = ball;
        }
      }
    }
  }

#pragma unroll
  for (int m = 1; m < 16; m <<= 1) {
#pragma unroll
    for (int g = 0; g < 2; ++g)
#pragma unroll
      for (int r = 0; r < 4; ++r) {
        float w0 = __shfl_xor(v0[g][r], m), w1 = __shfl_xor(v1[g][r], m);
        int j0 = __shfl_xor(i0[g][r], m), j1 = __shfl_xor(i1[g][r], m);
        merge_top2(v0[g][r], i0[g][r], v1[g][r], i1[g][r], w0, j0, w1, j1);
      }
  }
  if (l15 == 0) {
#pragma unroll
    for (int g = 0; g < 2; ++g)
#pragma unroll
      for (int r = 0; r < 4; ++r) {
        int q = (g ? q1 : q0) + quad * 4 + r;
        topk2[h * NM + q] = make_int2(i0[g][r], i1[g][r]);
      }
  }
}

// ---------------------------------------------------------------------------
// K4: fp16 interleaved K/V gather, 4 (h,q) waves per block. Output written
// coalesced to acat [half][h][t][32].
// ---------------------------------------------------------------------------
__global__ __launch_bounds__(256) void k_attn(
    const _Float16* __restrict__ qcat, const _Float16* __restrict__ kv16,
    const int2* __restrict__ topk2, _Float16* __restrict__ acat) {
  __shared__ _Float16 kv_s[4][32 * 72];
  __shared__ float q_s[4][HE];
  __shared__ float attw[4][32];
  int wv = threadIdx.x >> 6;
  int tid = threadIdx.x & 63;
  int idx = blockIdx.x * 4 + wv;
  int h = idx >> 13, t = idx & (NM - 1);

  int2 tk = topk2[h * NM + t];

  if (tid < HE) {
    const _Float16* qr = &qcat[(h * NM + t) * 64];
    q_s[wv][tid] = (float)qr[tid] + (float)qr[32 + tid];
  }
#pragma unroll
  for (int i = 0; i < 4; ++i) {
    int g = tid + 64 * i;            // 0..255
    int j = g >> 3, seg = g & 7;     // token row j, 16B segment
    int ball = (j < 16) ? tk.x : tk.y;
    int m = j & 15;
    *(uint4*)&kv_s[wv][j * 72 + seg * 8] =
        *(const uint4*)&kv16[(h * NM + ball * BALL + m) * 64 + seg * 8];
  }
  __syncthreads();

  int j = tid & 31, half = tid >> 5;
  int e0 = half * 16;
  float partial = 0.f;
  {
    f16x8 ka = *(const f16x8*)&kv_s[wv][j * 72 + e0];
    f16x8 kb = *(const f16x8*)&kv_s[wv][j * 72 + e0 + 8];
#pragma unroll
    for (int e = 0; e < 8; ++e) {
      partial += q_s[wv][e0 + e] * (float)ka[e];
      partial += q_s[wv][e0 + 8 + e] * (float)kb[e];
    }
  }
  partial += __shfl_xor(partial, 32);
  float logit = partial * 0.17677669529663687f;  // 1/sqrt(32)
  float mx = logit;
#pragma unroll
  for (int mk = 1; mk <= 16; mk <<= 1) mx = fmaxf(mx, __shfl_xor(mx, mk));
  float pexp = __expf(logit - mx);
  float sum = pexp;
#pragma unroll
  for (int mk = 1; mk <= 16; mk <<= 1) sum += __shfl_xor(sum, mk);
  float attn = pexp / sum;
  if (tid < 32) attw[wv][j] = attn;
  __syncthreads();

  int e = tid & 31, j0 = half * 16;
  float po = 0.f;
#pragma unroll
  for (int jj = 0; jj < 16; ++jj)
    po += attw[wv][j0 + jj] * (float)kv_s[wv][(j0 + jj) * 72 + 32 + e];
  po += __shfl_xor(po, 32);
  if (tid < 32) {
    _Float16 hi, lo;
    f2h_split(po, hi, lo);
    acat[(h * NM + t) * 32 + e] = hi;               // half 0
    acat[((NH + h) * NM + t) * 32 + e] = lo;        // half 1
  }
}

extern "C" void kernel_launch(void* const* d_in, const int* in_sizes, int n_in,
                              void* d_out, int out_size, void* d_ws,
                              size_t ws_size, hipStream_t stream) {
  const float* x = (const float*)d_in[0];
  const float* pos = (const float*)d_in[1];
  const float* Wqkv = (const float*)d_in[2];
  const float* bqkv = (const float*)d_in[3];
  const float* Wpe = (const float*)d_in[4];
  const float* bpe = (const float*)d_in[5];
  const float* Wproj = (const float*)d_in[6];
  const float* bproj = (const float*)d_in[7];
  float* out = (float*)d_out;

  float* kbuf = (float*)d_ws;                         // 8 MB (kmean only)
  _Float16* kv16 = (_Float16*)(kbuf + NH * NM * HE);  // 8 MB
  _Float16* qcat = kv16 + NH * NM * 64;               // 8 MB
  _Float16* kmc = qcat + NH * NM * 64;                // 512 KB
  int2* topk2 = (int2*)(kmc + NH * NBALLS * 64);      // 512 KB
  _Float16* xcat = (_Float16*)(topk2 + NH * NM);      // 8 MB
  _Float16* acat = xcat + NM * 512;                   // 8 MB
  _Float16* Bq = acat + 2 * NH * NM * 32;             // 1.2 MB
  _Float16* Bp = Bq + 768 * 768;                      // 0.4 MB

  k_prep<<<NBALLS + 1024, 256, 0, stream>>>(x, pos, Wpe, bpe, xcat, Wqkv,
                                            Wproj, Bq, Bp);
  k_qkv_gemm<<<dim3(NM / 128, 768 / 64), 256, 0, stream>>>(xcat, Bq, bqkv,
                                                           qcat, kbuf, kv16);
  k_kmean<<<(NH * NBALLS) / 8, 256, 0, stream>>>(kbuf, kmc);
  k_sim_topk<<<dim3(NM / 128, NH), 256, 0, stream>>>(qcat, kmc, topk2);
  k_attn<<<NH * NM / 4, 256, 0, stream>>>(qcat, kv16, topk2, acat);
  k_proj<<<dim3(NM / 128, DIM / 64), 256, 0, stream>>>(acat, Bp, bproj, out);
}

// Round 11
// 154.306 us; speedup vs baseline: 2.1249x; 1.0390x over previous
//
#include <hip/hip_runtime.h>

#define DIM 256
#define NH 8
#define HE 32          // head dim E
#define BALL 16        // ball size M
#define NBALLS 512
#define NM 8192

typedef _Float16 f16x8 __attribute__((ext_vector_type(8)));
typedef float f32x4 __attribute__((ext_vector_type(4)));

// fp16 2-term split: x = hi + lo, residual ~2^-24 |x| (fp32-quality)
__device__ __forceinline__ void f2h_split(float val, _Float16& hi,
                                          _Float16& lo) {
  hi = (_Float16)val;
  lo = (_Float16)(val - (float)hi);
}

// async global->LDS, 16B per lane; LDS dest = wave-uniform base + lane*16
__device__ __forceinline__ void gld_lds16(_Float16* lds, const _Float16* g) {
  __builtin_amdgcn_global_load_lds(
      (const __attribute__((address_space(1))) unsigned int*)g,
      (__attribute__((address_space(3))) unsigned int*)lds, 16, 0, 0);
}

// ---------------------------------------------------------------------------
// K1 (fused): blocks [0,512): posembed -> xcat[t][hi256|lo256]
//             blocks [512,1536): weight split -> Bq/Bp concatenated-K fp16
//             (B layout [N][768]: 0:256=hi, 256:512=hi dup, 512:768=lo)
// ---------------------------------------------------------------------------
__global__ __launch_bounds__(256) void k_prep(
    const float* __restrict__ x, const float* __restrict__ pos,
    const float* __restrict__ Wpe, const float* __restrict__ bpe,
    _Float16* __restrict__ xcat, const float* __restrict__ Wq,
    const float* __restrict__ Wp, _Float16* __restrict__ Bq,
    _Float16* __restrict__ Bp) {
  if (blockIdx.x >= NBALLS) {
    int n = blockIdx.x - NBALLS;  // 0..1023
    int k = threadIdx.x;
    if (n < 768) {
      _Float16 hi, lo;
      f2h_split(Wq[n * 256 + k], hi, lo);
      Bq[n * 768 + k] = hi;
      Bq[n * 768 + 256 + k] = hi;
      Bq[n * 768 + 512 + k] = lo;
    } else {
      int r = n - 768;
      _Float16 hi, lo;
      f2h_split(Wp[r * 256 + k], hi, lo);
      Bp[r * 768 + k] = hi;
      Bp[r * 768 + 256 + k] = hi;
      Bp[r * 768 + 512 + k] = lo;
    }
    return;
  }
  __shared__ float ps[BALL * 3];
  __shared__ float mean_s[3];
  int ball = blockIdx.x;
  int tid = threadIdx.x;
  if (tid < BALL * 3) ps[tid] = pos[ball * BALL * 3 + tid];
  __syncthreads();
  if (tid < 3) {
    float s = 0.f;
    for (int m = 0; m < BALL; ++m) s += ps[m * 3 + tid];
    mean_s[tid] = s * (1.f / BALL);
  }
  __syncthreads();
  int d = tid;
  float w0 = Wpe[d * 3 + 0], w1 = Wpe[d * 3 + 1], w2 = Wpe[d * 3 + 2];
  float bp = bpe[d];
  float m0 = mean_s[0], m1 = mean_s[1], m2 = mean_s[2];
  for (int m = 0; m < BALL; ++m) {
    int t = ball * BALL + m;
    float r0 = ps[m * 3 + 0] - m0;
    float r1 = ps[m * 3 + 1] - m1;
    float r2 = ps[m * 3 + 2] - m2;
    float val = x[t * DIM + d] + r0 * w0 + r1 * w1 + r2 * w2 + bp;
    _Float16 hi, lo;
    f2h_split(val, hi, lo);
    xcat[t * 512 + d] = hi;
    xcat[t * 512 + 256 + d] = lo;
  }
}

// ---------------------------------------------------------------------------
// Split-fp16 MFMA GEMM core with async LDS staging + XOR-swizzled layout.
// Tile 128x64, BK=64, wave-tile 64x32 = 4x2 mfma_f32_16x16x32_f16.
// ---------------------------------------------------------------------------
#define TBK 64

template <typename AF, typename BF, typename Epi>
__device__ __forceinline__ void gemm_core(AF a_addr, BF b_addr,
                                          const float* __restrict__ bias,
                                          int m0, int n0, Epi epi) {
  __shared__ _Float16 As[128 * 64];
  __shared__ _Float16 Bs[64 * 64];
  int tid = threadIdx.x;
  int w = tid >> 6, lane = tid & 63;
  int wm = (w >> 1) * 64, wn = (w & 1) * 32;
  int l15 = lane & 15, quad = lane >> 4;
  int sw = l15 & 7;  // swizzle key for all fragment rows (row&7 == l15&7)
  f32x4 acc[4][2] = {};
  for (int k0 = 0; k0 < 768; k0 += TBK) {
    int ak0 = (k0 < 512) ? k0 : (k0 - 512);
    if (k0) __syncthreads();
#pragma unroll
    for (int t = 0; t < 4; ++t) {
      int f = tid + 256 * t;  // 0..1023
      int row = f >> 3, sg = (f & 7) ^ (row & 7);
      gld_lds16(&As[f * 8], a_addr(m0 + row, ak0 + sg * 8));
    }
#pragma unroll
    for (int t = 0; t < 2; ++t) {
      int f = tid + 256 * t;  // 0..511
      int row = f >> 3, sg = (f & 7) ^ (row & 7);
      gld_lds16(&Bs[f * 8], b_addr(n0 + row, k0 + sg * 8));
    }
    __syncthreads();
#pragma unroll
    for (int kk = 0; kk < TBK; kk += 32) {
      int ls = (kk >> 3) + quad;          // logical 16B segment
      int psg = (ls ^ sw) * 8;            // physical element offset
      f16x8 bfr0 = *(const f16x8*)&Bs[(wn + l15) * 64 + psg];
      f16x8 bfr1 = *(const f16x8*)&Bs[(wn + 16 + l15) * 64 + psg];
#pragma unroll
      for (int mt = 0; mt < 4; ++mt) {
        f16x8 afr = *(const f16x8*)&As[(wm + mt * 16 + l15) * 64 + psg];
        acc[mt][0] = __builtin_amdgcn_mfma_f32_16x16x32_f16(afr, bfr0,
                                                            acc[mt][0], 0, 0,
                                                            0);
        acc[mt][1] = __builtin_amdgcn_mfma_f32_16x16x32_f16(afr, bfr1,
                                                            acc[mt][1], 0, 0,
                                                            0);
      }
    }
  }
#pragma unroll
  for (int mt = 0; mt < 4; ++mt) {
#pragma unroll
    for (int nt = 0; nt < 2; ++nt) {
      int col = n0 + wn + nt * 16 + l15;
      float bv = bias[col];
#pragma unroll
      for (int r = 0; r < 4; ++r) {
        int row = m0 + wm + mt * 16 + quad * 4 + r;
        epi(row, col, acc[mt][nt][r] + bv);
      }
    }
  }
}

// K2: qkv GEMM. q -> qcat split-fp16; k -> kbuf fp32 (kmean) + kv16 fp16;
// v -> kv16 fp16 only.
__global__ __launch_bounds__(256) void k_qkv_gemm(
    const _Float16* __restrict__ A, const _Float16* __restrict__ B,
    const float* __restrict__ bias, _Float16* __restrict__ qcat,
    float* __restrict__ kbuf, _Float16* __restrict__ kv16) {
  int m0 = blockIdx.x * 128, n0 = blockIdx.y * 64;
  gemm_core(
      [=](int r, int k) { return &A[r * 512 + k]; },
      [=](int r, int k) { return &B[r * 768 + k]; }, bias, m0, n0,
      [=](int row, int col, float val) {
        int c = col % 3;
        int rr = col / 3;
        int e = rr & 31;
        int h = rr >> 5;
        if (c == 0) {
          _Float16 hi, lo;
          f2h_split(val, hi, lo);
          qcat[(h * NM + row) * 64 + e] = hi;
          qcat[(h * NM + row) * 64 + 32 + e] = lo;
        } else if (c == 1) {
          kbuf[(h * NM + row) * HE + e] = val;
          kv16[(h * NM + row) * 64 + e] = (_Float16)val;
        } else {
          kv16[(h * NM + row) * 64 + 32 + e] = (_Float16)val;
        }
      });
}

// K5: proj GEMM. A = acat in [half][h][t][32] layout (coalesced attn writes)
__global__ __launch_bounds__(256) void k_proj(
    const _Float16* __restrict__ acat, const _Float16* __restrict__ B,
    const float* __restrict__ bias, float* __restrict__ out) {
  int m0 = blockIdx.x * 128, n0 = blockIdx.y * 64;
  gemm_core(
      [=](int r, int k) {
        int half = k >> 8, hh = (k >> 5) & 7, e0 = k & 31;
        return &acat[((half * NH + hh) * NM + r) * 32 + e0];
      },
      [=](int r, int k) { return &B[r * 768 + k]; }, bias, m0, n0,
      [=](int row, int col, float val) { out[row * DIM + col] = val; });
}

// K2b: kmc[h][ball][hi32|lo32] = split-fp16 of mean over m of kbuf (fp32)
__global__ __launch_bounds__(256) void k_kmean(
    const float* __restrict__ kbuf, _Float16* __restrict__ kmc) {
  int tid = threadIdx.x;
  int gb = blockIdx.x * 8 + (tid >> 5);  // h*512 + ball
  int e = tid & 31;
  int h = gb >> 9, ball = gb & 511;
  float s = 0.f;
#pragma unroll
  for (int m = 0; m < BALL; ++m)
    s += kbuf[(h * NM + ball * BALL + m) * HE + e];
  float mean = s * (1.f / BALL);
  _Float16 hi, lo;
  f2h_split(mean, hi, lo);
  kmc[gb * 64 + e] = hi;
  kmc[gb * 64 + 32 + e] = lo;
}

// ---------------------------------------------------------------------------
// K3 v3: sim+top2 on MFMA, branchless top-2, 512-thread blocks.
// 8 waves x 16 queries = 128 queries/block; grid (64, NH) -> 16 waves/CU.
// kmean staged in 4 chunks of 128 balls (16 KB) shared by all 8 waves.
// Per tile: 3 MFMAs + 4 cndmask-only top-2 updates (no branches).
// ---------------------------------------------------------------------------
__global__ __launch_bounds__(512) void k_sim_topk(
    const _Float16* __restrict__ qcat, const _Float16* __restrict__ kmc,
    int2* __restrict__ topk2) {
  __shared__ _Float16 km_s[128 * 64];
  int tid = threadIdx.x;  // 0..511
  int h = blockIdx.y;
  int wv = tid >> 6, lane = tid & 63;
  int l15 = lane & 15, quad = lane >> 4;
  int sw = l15 & 7;
  int q0 = blockIdx.x * 128 + wv * 16;

  const _Float16* qr = &qcat[(h * NM + q0 + l15) * 64];
  f16x8 qhi = *(const f16x8*)&qr[quad * 8];
  f16x8 qlo = *(const f16x8*)&qr[32 + quad * 8];

  float v0[4], v1[4];
  int i0[4], i1[4];
#pragma unroll
  for (int r = 0; r < 4; ++r) {
    v0[r] = -1e30f; v1[r] = -1e30f; i0[r] = 0; i1[r] = 0;
  }

  for (int ch = 0; ch < 4; ++ch) {
    if (ch) __syncthreads();
#pragma unroll
    for (int t = 0; t < 2; ++t) {
      int f = tid + 512 * t;  // 0..1023
      int row = f >> 3, sg = (f & 7) ^ (row & 7);
      gld_lds16(&km_s[f * 8],
                &kmc[(h * NBALLS + ch * 128 + row) * 64 + sg * 8]);
    }
    __syncthreads();

#pragma unroll
    for (int tile = 0; tile < 8; ++tile) {
      const _Float16* bb = &km_s[(tile * 16 + l15) * 64];
      f16x8 bhi = *(const f16x8*)&bb[(quad ^ sw) * 8];
      f16x8 blo = *(const f16x8*)&bb[((4 + quad) ^ sw) * 8];
      f32x4 acc = {};
      acc = __builtin_amdgcn_mfma_f32_16x16x32_f16(qhi, bhi, acc, 0, 0, 0);
      acc = __builtin_amdgcn_mfma_f32_16x16x32_f16(qlo, bhi, acc, 0, 0, 0);
      acc = __builtin_amdgcn_mfma_f32_16x16x32_f16(qhi, blo, acc, 0, 0, 0);
      int ball = ch * 128 + tile * 16 + l15;
#pragma unroll
      for (int r = 0; r < 4; ++r) {
        float s = acc[r];
        bool gt0 = s > v0[r];       // strict: earlier index wins ties
        bool gt1 = s > v1[r];
        float nv1 = gt0 ? v0[r] : (gt1 ? s : v1[r]);
        int ni1 = gt0 ? i0[r] : (gt1 ? ball : i1[r]);
        v0[r] = gt0 ? s : v0[r];
        i0[r] = gt0 ? ball : i0[r];
        v1[r] = nv1;
        i1[r] = ni1;
      }
    }
  }

  // branchless butterfly merge across the 16 lanes of each quad-group
#pragma unroll
  for (int m = 1; m < 16; m <<= 1) {
#pragma unroll
    for (int r = 0; r < 4; ++r) {
      float w0 = __shfl_xor(v0[r], m), w1 = __shfl_xor(v1[r], m);
      int j0 = __shfl_xor(i0[r], m), j1 = __shfl_xor(i1[r], m);
      bool a = w0 > v0[r];            // tie keeps accumulator side
      float c2v = a ? v0[r] : w0;     // loser's top1
      int c2i = a ? i0[r] : j0;
      float o2v = a ? w1 : v1[r];     // winner's top2
      int o2i = a ? j1 : i1[r];
      v0[r] = a ? w0 : v0[r];
      i0[r] = a ? j0 : i0[r];
      bool b2 = c2v > o2v;
      v1[r] = b2 ? c2v : o2v;
      i1[r] = b2 ? c2i : o2i;
    }
  }
  if (l15 == 0) {
#pragma unroll
    for (int r = 0; r < 4; ++r) {
      int q = q0 + quad * 4 + r;
      topk2[h * NM + q] = make_int2(i0[r], i1[r]);
    }
  }
}

// ---------------------------------------------------------------------------
// K4: fp16 interleaved K/V gather, 4 (h,q) waves per block. Output written
// coalesced to acat [half][h][t][32].
// ---------------------------------------------------------------------------
__global__ __launch_bounds__(256) void k_attn(
    const _Float16* __restrict__ qcat, const _Float16* __restrict__ kv16,
    const int2* __restrict__ topk2, _Float16* __restrict__ acat) {
  __shared__ _Float16 kv_s[4][32 * 72];
  __shared__ float q_s[4][HE];
  __shared__ float attw[4][32];
  int wv = threadIdx.x >> 6;
  int tid = threadIdx.x & 63;
  int idx = blockIdx.x * 4 + wv;
  int h = idx >> 13, t = idx & (NM - 1);

  int2 tk = topk2[h * NM + t];

  if (tid < HE) {
    const _Float16* qr = &qcat[(h * NM + t) * 64];
    q_s[wv][tid] = (float)qr[tid] + (float)qr[32 + tid];
  }
#pragma unroll
  for (int i = 0; i < 4; ++i) {
    int g = tid + 64 * i;            // 0..255
    int j = g >> 3, seg = g & 7;     // token row j, 16B segment
    int ball = (j < 16) ? tk.x : tk.y;
    int m = j & 15;
    *(uint4*)&kv_s[wv][j * 72 + seg * 8] =
        *(const uint4*)&kv16[(h * NM + ball * BALL + m) * 64 + seg * 8];
  }
  __syncthreads();

  int j = tid & 31, half = tid >> 5;
  int e0 = half * 16;
  float partial = 0.f;
  {
    f16x8 ka = *(const f16x8*)&kv_s[wv][j * 72 + e0];
    f16x8 kb = *(const f16x8*)&kv_s[wv][j * 72 + e0 + 8];
#pragma unroll
    for (int e = 0; e < 8; ++e) {
      partial += q_s[wv][e0 + e] * (float)ka[e];
      partial += q_s[wv][e0 + 8 + e] * (float)kb[e];
    }
  }
  partial += __shfl_xor(partial, 32);
  float logit = partial * 0.17677669529663687f;  // 1/sqrt(32)
  float mx = logit;
#pragma unroll
  for (int mk = 1; mk <= 16; mk <<= 1) mx = fmaxf(mx, __shfl_xor(mx, mk));
  float pexp = __expf(logit - mx);
  float sum = pexp;
#pragma unroll
  for (int mk = 1; mk <= 16; mk <<= 1) sum += __shfl_xor(sum, mk);
  float attn = pexp / sum;
  if (tid < 32) attw[wv][j] = attn;
  __syncthreads();

  int e = tid & 31, j0 = half * 16;
  float po = 0.f;
#pragma unroll
  for (int jj = 0; jj < 16; ++jj)
    po += attw[wv][j0 + jj] * (float)kv_s[wv][(j0 + jj) * 72 + 32 + e];
  po += __shfl_xor(po, 32);
  if (tid < 32) {
    _Float16 hi, lo;
    f2h_split(po, hi, lo);
    acat[(h * NM + t) * 32 + e] = hi;               // half 0
    acat[((NH + h) * NM + t) * 32 + e] = lo;        // half 1
  }
}

extern "C" void kernel_launch(void* const* d_in, const int* in_sizes, int n_in,
                              void* d_out, int out_size, void* d_ws,
                              size_t ws_size, hipStream_t stream) {
  const float* x = (const float*)d_in[0];
  const float* pos = (const float*)d_in[1];
  const float* Wqkv = (const float*)d_in[2];
  const float* bqkv = (const float*)d_in[3];
  const float* Wpe = (const float*)d_in[4];
  const float* bpe = (const float*)d_in[5];
  const float* Wproj = (const float*)d_in[6];
  const float* bproj = (const float*)d_in[7];
  float* out = (float*)d_out;

  float* kbuf = (float*)d_ws;                         // 8 MB (kmean only)
  _Float16* kv16 = (_Float16*)(kbuf + NH * NM * HE);  // 8 MB
  _Float16* qcat = kv16 + NH * NM * 64;               // 8 MB
  _Float16* kmc = qcat + NH * NM * 64;                // 512 KB
  int2* topk2 = (int2*)(kmc + NH * NBALLS * 64);      // 512 KB
  _Float16* xcat = (_Float16*)(topk2 + NH * NM);      // 8 MB
  _Float16* acat = xcat + NM * 512;                   // 8 MB
  _Float16* Bq = acat + 2 * NH * NM * 32;             // 1.2 MB
  _Float16* Bp = Bq + 768 * 768;                      // 0.4 MB

  k_prep<<<NBALLS + 1024, 256, 0, stream>>>(x, pos, Wpe, bpe, xcat, Wqkv,
                                            Wproj, Bq, Bp);
  k_qkv_gemm<<<dim3(NM / 128, 768 / 64), 256, 0, stream>>>(xcat, Bq, bqkv,
                                                           qcat, kbuf, kv16);
  k_kmean<<<(NH * NBALLS) / 8, 256, 0, stream>>>(kbuf, kmc);
  k_sim_topk<<<dim3(NM / 128, NH), 512, 0, stream>>>(qcat, kmc, topk2);
  k_attn<<<NH * NM / 4, 256, 0, stream>>>(qcat, kv16, topk2, acat);
  k_proj<<<dim3(NM / 128, DIM / 64), 256, 0, stream>>>(acat, Bp, bproj, out);
}

// Round 12
// 147.041 us; speedup vs baseline: 2.2299x; 1.0494x over previous
//
#include <hip/hip_runtime.h>

#define DIM 256
#define NH 8
#define HE 32          // head dim E
#define BALL 16        // ball size M
#define NBALLS 512
#define NM 8192

typedef _Float16 f16x8 __attribute__((ext_vector_type(8)));
typedef float f32x4 __attribute__((ext_vector_type(4)));

// fp16 2-term split: x = hi + lo, residual ~2^-24 |x| (fp32-quality)
__device__ __forceinline__ void f2h_split(float val, _Float16& hi,
                                          _Float16& lo) {
  hi = (_Float16)val;
  lo = (_Float16)(val - (float)hi);
}

// async global->LDS, 16B per lane; LDS dest = wave-uniform base + lane*16
__device__ __forceinline__ void gld_lds16(_Float16* lds, const _Float16* g) {
  __builtin_amdgcn_global_load_lds(
      (const __attribute__((address_space(1))) unsigned int*)g,
      (__attribute__((address_space(3))) unsigned int*)lds, 16, 0, 0);
}

// ---------------------------------------------------------------------------
// K1 (fused): blocks [0,512): posembed -> xcat[t][hi256|lo256]
//   blocks [512,1536): weight split -> Bq/Bp concatenated-K fp16.
//   Bq rows are PERMUTED component-major: row n' = c*256 + h*32 + e holds
//   source row o = h*96 + e*3 + c  ->  GEMM output cols become [q|k|v].
// ---------------------------------------------------------------------------
__global__ __launch_bounds__(256) void k_prep(
    const float* __restrict__ x, const float* __restrict__ pos,
    const float* __restrict__ Wpe, const float* __restrict__ bpe,
    _Float16* __restrict__ xcat, const float* __restrict__ Wq,
    const float* __restrict__ Wp, _Float16* __restrict__ Bq,
    _Float16* __restrict__ Bp) {
  if (blockIdx.x >= NBALLS) {
    int n = blockIdx.x - NBALLS;  // 0..1023
    int k = threadIdx.x;
    if (n < 768) {
      int c = n % 3, rr = n / 3;
      int e = rr & 31, h = rr >> 5;
      int np = c * 256 + h * 32 + e;  // permuted destination row
      _Float16 hi, lo;
      f2h_split(Wq[n * 256 + k], hi, lo);
      Bq[np * 768 + k] = hi;
      Bq[np * 768 + 256 + k] = hi;
      Bq[np * 768 + 512 + k] = lo;
    } else {
      int r = n - 768;
      _Float16 hi, lo;
      f2h_split(Wp[r * 256 + k], hi, lo);
      Bp[r * 768 + k] = hi;
      Bp[r * 768 + 256 + k] = hi;
      Bp[r * 768 + 512 + k] = lo;
    }
    return;
  }
  __shared__ float ps[BALL * 3];
  __shared__ float mean_s[3];
  int ball = blockIdx.x;
  int tid = threadIdx.x;
  if (tid < BALL * 3) ps[tid] = pos[ball * BALL * 3 + tid];
  __syncthreads();
  if (tid < 3) {
    float s = 0.f;
    for (int m = 0; m < BALL; ++m) s += ps[m * 3 + tid];
    mean_s[tid] = s * (1.f / BALL);
  }
  __syncthreads();
  int d = tid;
  float w0 = Wpe[d * 3 + 0], w1 = Wpe[d * 3 + 1], w2 = Wpe[d * 3 + 2];
  float bp = bpe[d];
  float m0 = mean_s[0], m1 = mean_s[1], m2 = mean_s[2];
  for (int m = 0; m < BALL; ++m) {
    int t = ball * BALL + m;
    float r0 = ps[m * 3 + 0] - m0;
    float r1 = ps[m * 3 + 1] - m1;
    float r2 = ps[m * 3 + 2] - m2;
    float val = x[t * DIM + d] + r0 * w0 + r1 * w1 + r2 * w2 + bp;
    _Float16 hi, lo;
    f2h_split(val, hi, lo);
    xcat[t * 512 + d] = hi;
    xcat[t * 512 + 256 + d] = lo;
  }
}

// ---------------------------------------------------------------------------
// Split-fp16 MFMA GEMM core, async LDS staging + XOR swizzle.
// Tile 128x64, BK=64, wave-tile 64x32 = 4x2 mfma_f32_16x16x32_f16.
// Tile-level epilogue: epi(acc, wm, wn, l15, quad).
// ---------------------------------------------------------------------------
#define TBK 64

template <typename AF, typename BF, typename Epi>
__device__ __forceinline__ void gemm_core(AF a_addr, BF b_addr, int m0,
                                          int n0, Epi epi) {
  __shared__ _Float16 As[128 * 64];
  __shared__ _Float16 Bs[64 * 64];
  int tid = threadIdx.x;
  int w = tid >> 6, lane = tid & 63;
  int wm = (w >> 1) * 64, wn = (w & 1) * 32;
  int l15 = lane & 15, quad = lane >> 4;
  int sw = l15 & 7;
  f32x4 acc[4][2] = {};
  for (int k0 = 0; k0 < 768; k0 += TBK) {
    int ak0 = (k0 < 512) ? k0 : (k0 - 512);
    if (k0) __syncthreads();
#pragma unroll
    for (int t = 0; t < 4; ++t) {
      int f = tid + 256 * t;  // 0..1023
      int row = f >> 3, sg = (f & 7) ^ (row & 7);
      gld_lds16(&As[f * 8], a_addr(m0 + row, ak0 + sg * 8));
    }
#pragma unroll
    for (int t = 0; t < 2; ++t) {
      int f = tid + 256 * t;  // 0..511
      int row = f >> 3, sg = (f & 7) ^ (row & 7);
      gld_lds16(&Bs[f * 8], b_addr(n0 + row, k0 + sg * 8));
    }
    __syncthreads();
#pragma unroll
    for (int kk = 0; kk < TBK; kk += 32) {
      int ls = (kk >> 3) + quad;
      int psg = (ls ^ sw) * 8;
      f16x8 bfr0 = *(const f16x8*)&Bs[(wn + l15) * 64 + psg];
      f16x8 bfr1 = *(const f16x8*)&Bs[(wn + 16 + l15) * 64 + psg];
#pragma unroll
      for (int mt = 0; mt < 4; ++mt) {
        f16x8 afr = *(const f16x8*)&As[(wm + mt * 16 + l15) * 64 + psg];
        acc[mt][0] = __builtin_amdgcn_mfma_f32_16x16x32_f16(afr, bfr0,
                                                            acc[mt][0], 0, 0,
                                                            0);
        acc[mt][1] = __builtin_amdgcn_mfma_f32_16x16x32_f16(afr, bfr1,
                                                            acc[mt][1], 0, 0,
                                                            0);
      }
    }
  }
  epi(acc, wm, wn, l15, quad);
}

// K2: qkv GEMM with permuted-B output cols [q256|k256|v256].
// q -> qcat split-fp16; k -> kv16[..e] + fused kmean -> kmc; v -> kv16[..32+e]
__global__ __launch_bounds__(256) void k_qkv_gemm(
    const _Float16* __restrict__ A, const _Float16* __restrict__ B,
    const float* __restrict__ bias, _Float16* __restrict__ qcat,
    _Float16* __restrict__ kmc, _Float16* __restrict__ kv16) {
  int m0 = blockIdx.x * 128, n0 = blockIdx.y * 64;
  int c = n0 >> 8;  // block-uniform component: 0=q, 1=k, 2=v
  gemm_core(
      [=](int r, int k) { return &A[r * 512 + k]; },
      [=](int r, int k) { return &B[r * 768 + k]; }, m0, n0,
      [=](f32x4 (&acc)[4][2], int wm, int wn, int l15, int quad) {
#pragma unroll
        for (int nt = 0; nt < 2; ++nt) {
          int col = n0 + wn + nt * 16 + l15;
          int cc = col & 255;
          int e = cc & 31, h = cc >> 5;
          float bv = bias[h * 96 + e * 3 + c];
#pragma unroll
          for (int mt = 0; mt < 4; ++mt) {
            int rb = m0 + wm + mt * 16;
            if (c == 0) {
#pragma unroll
              for (int r = 0; r < 4; ++r) {
                int row = rb + quad * 4 + r;
                _Float16 hi, lo;
                f2h_split(acc[mt][nt][r] + bv, hi, lo);
                qcat[(h * NM + row) * 64 + e] = hi;
                qcat[(h * NM + row) * 64 + 32 + e] = lo;
              }
            } else if (c == 1) {
              float s = 0.f;
#pragma unroll
              for (int r = 0; r < 4; ++r) {
                int row = rb + quad * 4 + r;
                float val = acc[mt][nt][r] + bv;
                kv16[(h * NM + row) * 64 + e] = (_Float16)val;
                s += acc[mt][nt][r];
              }
              s += __shfl_xor(s, 16);
              s += __shfl_xor(s, 32);
              if (quad == 0) {
                int ball = rb >> 4;
                _Float16 hi, lo;
                f2h_split(s * (1.f / BALL) + bv, hi, lo);
                kmc[(h * NBALLS + ball) * 64 + e] = hi;
                kmc[(h * NBALLS + ball) * 64 + 32 + e] = lo;
              }
            } else {
#pragma unroll
              for (int r = 0; r < 4; ++r) {
                int row = rb + quad * 4 + r;
                kv16[(h * NM + row) * 64 + 32 + e] =
                    (_Float16)(acc[mt][nt][r] + bv);
              }
            }
          }
        }
      });
}

// K5: proj GEMM. A = acat in [half][h][t][32] layout (coalesced attn writes)
__global__ __launch_bounds__(256) void k_proj(
    const _Float16* __restrict__ acat, const _Float16* __restrict__ B,
    const float* __restrict__ bias, float* __restrict__ out) {
  int m0 = blockIdx.x * 128, n0 = blockIdx.y * 64;
  gemm_core(
      [=](int r, int k) {
        int half = k >> 8, hh = (k >> 5) & 7, e0 = k & 31;
        return &acat[((half * NH + hh) * NM + r) * 32 + e0];
      },
      [=](int r, int k) { return &B[r * 768 + k]; }, m0, n0,
      [=](f32x4 (&acc)[4][2], int wm, int wn, int l15, int quad) {
#pragma unroll
        for (int nt = 0; nt < 2; ++nt) {
          int col = n0 + wn + nt * 16 + l15;
          float bv = bias[col];
#pragma unroll
          for (int mt = 0; mt < 4; ++mt) {
#pragma unroll
            for (int r = 0; r < 4; ++r) {
              int row = m0 + wm + mt * 16 + quad * 4 + r;
              out[row * DIM + col] = acc[mt][nt][r] + bv;
            }
          }
        }
      });
}

// ---------------------------------------------------------------------------
// K3: sim+top2 on MFMA, branchless top-2, 512-thread blocks.
// ---------------------------------------------------------------------------
__global__ __launch_bounds__(512) void k_sim_topk(
    const _Float16* __restrict__ qcat, const _Float16* __restrict__ kmc,
    int2* __restrict__ topk2) {
  __shared__ _Float16 km_s[128 * 64];
  int tid = threadIdx.x;  // 0..511
  int h = blockIdx.y;
  int wv = tid >> 6, lane = tid & 63;
  int l15 = lane & 15, quad = lane >> 4;
  int sw = l15 & 7;
  int q0 = blockIdx.x * 128 + wv * 16;

  const _Float16* qr = &qcat[(h * NM + q0 + l15) * 64];
  f16x8 qhi = *(const f16x8*)&qr[quad * 8];
  f16x8 qlo = *(const f16x8*)&qr[32 + quad * 8];

  float v0[4], v1[4];
  int i0[4], i1[4];
#pragma unroll
  for (int r = 0; r < 4; ++r) {
    v0[r] = -1e30f; v1[r] = -1e30f; i0[r] = 0; i1[r] = 0;
  }

  for (int ch = 0; ch < 4; ++ch) {
    if (ch) __syncthreads();
#pragma unroll
    for (int t = 0; t < 2; ++t) {
      int f = tid + 512 * t;  // 0..1023
      int row = f >> 3, sg = (f & 7) ^ (row & 7);
      gld_lds16(&km_s[f * 8],
                &kmc[(h * NBALLS + ch * 128 + row) * 64 + sg * 8]);
    }
    __syncthreads();

#pragma unroll
    for (int tile = 0; tile < 8; ++tile) {
      const _Float16* bb = &km_s[(tile * 16 + l15) * 64];
      f16x8 bhi = *(const f16x8*)&bb[(quad ^ sw) * 8];
      f16x8 blo = *(const f16x8*)&bb[((4 + quad) ^ sw) * 8];
      f32x4 acc = {};
      acc = __builtin_amdgcn_mfma_f32_16x16x32_f16(qhi, bhi, acc, 0, 0, 0);
      acc = __builtin_amdgcn_mfma_f32_16x16x32_f16(qlo, bhi, acc, 0, 0, 0);
      acc = __builtin_amdgcn_mfma_f32_16x16x32_f16(qhi, blo, acc, 0, 0, 0);
      int ball = ch * 128 + tile * 16 + l15;
#pragma unroll
      for (int r = 0; r < 4; ++r) {
        float s = acc[r];
        bool gt0 = s > v0[r];       // strict: earlier index wins ties
        bool gt1 = s > v1[r];
        float nv1 = gt0 ? v0[r] : (gt1 ? s : v1[r]);
        int ni1 = gt0 ? i0[r] : (gt1 ? ball : i1[r]);
        v0[r] = gt0 ? s : v0[r];
        i0[r] = gt0 ? ball : i0[r];
        v1[r] = nv1;
        i1[r] = ni1;
      }
    }
  }

#pragma unroll
  for (int m = 1; m < 16; m <<= 1) {
#pragma unroll
    for (int r = 0; r < 4; ++r) {
      float w0 = __shfl_xor(v0[r], m), w1 = __shfl_xor(v1[r], m);
      int j0 = __shfl_xor(i0[r], m), j1 = __shfl_xor(i1[r], m);
      bool a = w0 > v0[r];            // tie keeps accumulator side
      float c2v = a ? v0[r] : w0;
      int c2i = a ? i0[r] : j0;
      float o2v = a ? w1 : v1[r];
      int o2i = a ? j1 : i1[r];
      v0[r] = a ? w0 : v0[r];
      i0[r] = a ? j0 : i0[r];
      bool b2 = c2v > o2v;
      v1[r] = b2 ? c2v : o2v;
      i1[r] = b2 ? c2i : o2i;
    }
  }
  if (l15 == 0) {
#pragma unroll
    for (int r = 0; r < 4; ++r) {
      int q = q0 + quad * 4 + r;
      topk2[h * NM + q] = make_int2(i0[r], i1[r]);
    }
  }
}

// ---------------------------------------------------------------------------
// K4: fp16 interleaved K/V gather, 4 (h,q) waves per block. Output written
// coalesced to acat [half][h][t][32].
// ---------------------------------------------------------------------------
__global__ __launch_bounds__(256) void k_attn(
    const _Float16* __restrict__ qcat, const _Float16* __restrict__ kv16,
    const int2* __restrict__ topk2, _Float16* __restrict__ acat) {
  __shared__ _Float16 kv_s[4][32 * 72];
  __shared__ float q_s[4][HE];
  __shared__ float attw[4][32];
  int wv = threadIdx.x >> 6;
  int tid = threadIdx.x & 63;
  int idx = blockIdx.x * 4 + wv;
  int h = idx >> 13, t = idx & (NM - 1);

  int2 tk = topk2[h * NM + t];

  if (tid < HE) {
    const _Float16* qr = &qcat[(h * NM + t) * 64];
    q_s[wv][tid] = (float)qr[tid] + (float)qr[32 + tid];
  }
#pragma unroll
  for (int i = 0; i < 4; ++i) {
    int g = tid + 64 * i;            // 0..255
    int j = g >> 3, seg = g & 7;     // token row j, 16B segment
    int ball = (j < 16) ? tk.x : tk.y;
    int m = j & 15;
    *(uint4*)&kv_s[wv][j * 72 + seg * 8] =
        *(const uint4*)&kv16[(h * NM + ball * BALL + m) * 64 + seg * 8];
  }
  __syncthreads();

  int j = tid & 31, half = tid >> 5;
  int e0 = half * 16;
  float partial = 0.f;
  {
    f16x8 ka = *(const f16x8*)&kv_s[wv][j * 72 + e0];
    f16x8 kb = *(const f16x8*)&kv_s[wv][j * 72 + e0 + 8];
#pragma unroll
    for (int e = 0; e < 8; ++e) {
      partial += q_s[wv][e0 + e] * (float)ka[e];
      partial += q_s[wv][e0 + 8 + e] * (float)kb[e];
    }
  }
  partial += __shfl_xor(partial, 32);
  float logit = partial * 0.17677669529663687f;  // 1/sqrt(32)
  float mx = logit;
#pragma unroll
  for (int mk = 1; mk <= 16; mk <<= 1) mx = fmaxf(mx, __shfl_xor(mx, mk));
  float pexp = __expf(logit - mx);
  float sum = pexp;
#pragma unroll
  for (int mk = 1; mk <= 16; mk <<= 1) sum += __shfl_xor(sum, mk);
  float attn = pexp / sum;
  if (tid < 32) attw[wv][j] = attn;
  __syncthreads();

  int e = tid & 31, j0 = half * 16;
  float po = 0.f;
#pragma unroll
  for (int jj = 0; jj < 16; ++jj)
    po += attw[wv][j0 + jj] * (float)kv_s[wv][(j0 + jj) * 72 + 32 + e];
  po += __shfl_xor(po, 32);
  if (tid < 32) {
    _Float16 hi, lo;
    f2h_split(po, hi, lo);
    acat[(h * NM + t) * 32 + e] = hi;               // half 0
    acat[((NH + h) * NM + t) * 32 + e] = lo;        // half 1
  }
}

extern "C" void kernel_launch(void* const* d_in, const int* in_sizes, int n_in,
                              void* d_out, int out_size, void* d_ws,
                              size_t ws_size, hipStream_t stream) {
  const float* x = (const float*)d_in[0];
  const float* pos = (const float*)d_in[1];
  const float* Wqkv = (const float*)d_in[2];
  const float* bqkv = (const float*)d_in[3];
  const float* Wpe = (const float*)d_in[4];
  const float* bpe = (const float*)d_in[5];
  const float* Wproj = (const float*)d_in[6];
  const float* bproj = (const float*)d_in[7];
  float* out = (float*)d_out;

  _Float16* kv16 = (_Float16*)d_ws;                   // 8 MB
  _Float16* qcat = kv16 + NH * NM * 64;               // 8 MB
  _Float16* kmc = qcat + NH * NM * 64;                // 512 KB
  int2* topk2 = (int2*)(kmc + NH * NBALLS * 64);      // 512 KB
  _Float16* xcat = (_Float16*)(topk2 + NH * NM);      // 8 MB
  _Float16* acat = xcat + NM * 512;                   // 8 MB
  _Float16* Bq = acat + 2 * NH * NM * 32;             // 1.2 MB
  _Float16* Bp = Bq + 768 * 768;                      // 0.4 MB

  k_prep<<<NBALLS + 1024, 256, 0, stream>>>(x, pos, Wpe, bpe, xcat, Wqkv,
                                            Wproj, Bq, Bp);
  k_qkv_gemm<<<dim3(NM / 128, 768 / 64), 256, 0, stream>>>(xcat, Bq, bqkv,
                                                           qcat, kmc, kv16);
  k_sim_topk<<<dim3(NM / 128, NH), 512, 0, stream>>>(qcat, kmc, topk2);
  k_attn<<<NH * NM / 4, 256, 0, stream>>>(qcat, kv16, topk2, acat);
  k_proj<<<dim3(NM / 128, DIM / 64), 256, 0, stream>>>(acat, Bp, bproj, out);
}